// Round 9
// baseline (831.725 us; speedup 1.0000x reference)
//
#include <hip/hip_runtime.h>
#include <math.h>

typedef unsigned short u16;
typedef unsigned int u32;
typedef __attribute__((ext_vector_type(4))) unsigned short u16x4;
typedef __attribute__((ext_vector_type(8))) short bf16x8;
typedef __attribute__((ext_vector_type(4))) float f32x4;

#define B_ 4
#define S_ 2048
#define D_ 1024
#define H_ 16
#define NT (B_*S_)
#define DFF 4096

static __device__ __forceinline__ float bf2f(u16 u) {
    return __uint_as_float(((u32)u) << 16);
}
static __device__ __forceinline__ u16 f2bf(float f) {
    u32 u = __float_as_uint(f);
    u32 r = (u + 0x7fffu + ((u >> 16) & 1u)) >> 16;
    return (u16)r;
}
// async 16B/lane global->LDS (LDS dest = wave-uniform base + lane*16)
static __device__ __forceinline__ void gload_lds16(const void* g, void* l) {
    __builtin_amdgcn_global_load_lds(
        (const __attribute__((address_space(1))) void*)g,
        (__attribute__((address_space(3))) void*)l, 16, 0, 0);
}
// tanh-form GELU via hw exp2 (validated R14: passed absmax 0.0625).
static __device__ __forceinline__ float gelu_fast(float x) {
    float x2 = x * x;
    float u = x * fmaf(0.044715f, x2, 1.0f);
    float e = exp2f(2.3022079f * u);
    float r = __builtin_amdgcn_rcpf(e + 1.0f);
    return x - x * r;
}

// raw barrier (no implicit vmcnt(0) drain, unlike __syncthreads) with
// compiler memory fences so C++ LDS reads can't be hoisted across it.
#define MBAR() do { asm volatile("" ::: "memory"); \
                    __builtin_amdgcn_s_barrier(); \
                    asm volatile("" ::: "memory"); } while (0)

// ------------------------------------------------- transpose fp32 -> bf16
__global__ void transpose_f2b4(const float* __restrict__ s0, const float* __restrict__ s1,
                               const float* __restrict__ s2, const float* __restrict__ s3,
                               u16* __restrict__ d0, u16* __restrict__ d1,
                               u16* __restrict__ d2, u16* __restrict__ d3,
                               int R, int C) {
    const float* in = s0; u16* out = d0;
    if (blockIdx.z == 1) { in = s1; out = d1; }
    else if (blockIdx.z == 2) { in = s2; out = d2; }
    else if (blockIdx.z == 3) { in = s3; out = d3; }
    __shared__ float t[32][33];
    int c0 = blockIdx.x * 32, r0 = blockIdx.y * 32;
    int x = threadIdx.x, y = threadIdx.y;
    #pragma unroll
    for (int i = 0; i < 4; i++)
        t[y + i*8][x] = in[(long)(r0 + y + i*8) * C + c0 + x];
    __syncthreads();
    #pragma unroll
    for (int i = 0; i < 4; i++)
        out[(long)(c0 + y + i*8) * R + r0 + x] = f2bf(t[x][y + i*8]);
}

__global__ void transpose_f2b(const float* __restrict__ in, u16* __restrict__ out,
                              int R, int C) {
    __shared__ float t[32][33];
    int c0 = blockIdx.x * 32, r0 = blockIdx.y * 32;
    int x = threadIdx.x, y = threadIdx.y;
    #pragma unroll
    for (int i = 0; i < 4; i++)
        t[y + i*8][x] = in[(long)(r0 + y + i*8) * C + c0 + x];
    __syncthreads();
    #pragma unroll
    for (int i = 0; i < 4; i++)
        out[(long)(c0 + y + i*8) * R + r0 + x] = f2bf(t[x][y + i*8]);
}

// V bf16 [B*S][D] -> Vt bf16 [B*H][64][S]. grid (S/32, 2, B*H), block (32,8)
__global__ void transpose_v(const u16* __restrict__ V, u16* __restrict__ Vt) {
    __shared__ u16 t[32][33];
    int z = blockIdx.z; int b = z >> 4, h = z & 15;
    int s0 = blockIdx.x * 32, d0 = blockIdx.y * 32;
    int x = threadIdx.x, y = threadIdx.y;
    const u16* in = V + ((long)b * S_ + s0) * D_ + h * 64 + d0;
    #pragma unroll
    for (int i = 0; i < 4; i++)
        t[y + i*8][x] = in[(long)(y + i*8) * D_ + x];
    __syncthreads();
    u16* out = Vt + ((long)z * 64 + d0) * S_ + s0;
    #pragma unroll
    for (int i = 0; i < 4; i++)
        out[(long)(y + i*8) * S_ + x] = t[x][y + i*8];
}

// ------------------------------------------------- layernorm (fp32 in, bf16 out)
__global__ __launch_bounds__(256) void ln_kernel(
    const float* __restrict__ X, const float* __restrict__ alpha,
    const float* __restrict__ beta, u16* __restrict__ Y) {
    int row = blockIdx.x, tid = threadIdx.x;
    float4 xv = ((const float4*)(X + (long)row * D_))[tid];
    float v[4] = {xv.x, xv.y, xv.z, xv.w};
    float s = 0.f, ss = 0.f;
    #pragma unroll
    for (int i = 0; i < 4; i++) { s += v[i]; ss += v[i]*v[i]; }
    #pragma unroll
    for (int off = 32; off >= 1; off >>= 1) {
        s += __shfl_xor(s, off);
        ss += __shfl_xor(ss, off);
    }
    __shared__ float red[8];
    __shared__ float stats[2];
    int w = tid >> 6;
    if ((tid & 63) == 0) { red[w] = s; red[4 + w] = ss; }
    __syncthreads();
    if (tid == 0) {
        float S = red[0] + red[1] + red[2] + red[3];
        float SS = red[4] + red[5] + red[6] + red[7];
        float mean = S * (1.f / D_);
        float var = SS * (1.f / D_) - mean * mean;
        stats[0] = mean; stats[1] = rsqrtf(var + 1e-5f);
    }
    __syncthreads();
    float mean = stats[0], rstd = stats[1];
    float4 av = ((const float4*)alpha)[tid];
    float4 bv = ((const float4*)beta)[tid];
    u16x4 o;
    o[0] = f2bf((v[0] - mean) * rstd * av.x + bv.x);
    o[1] = f2bf((v[1] - mean) * rstd * av.y + bv.y);
    o[2] = f2bf((v[2] - mean) * rstd * av.z + bv.z);
    o[3] = f2bf((v[3] - mean) * rstd * av.w + bv.w);
    *(u16x4*)(Y + (long)row * D_ + tid * 4) = o;
}

// ------------------------------------------------- GEMM 128^2 (Wo, W2)
// BASELINE m97 recipe, untouched. N=1024 shapes stay here.
#define BM 128
#define BN 128
#define BK 64

__global__ __launch_bounds__(256, 3) void gemm_bt(
    const u16* __restrict__ A,
    const u16* __restrict__ Bt0, const u16* __restrict__ Bt1, const u16* __restrict__ Bt2,
    void* __restrict__ C0, void* __restrict__ C1, void* __restrict__ C2,
    int M, int N, int K, int mode,
    const float* __restrict__ bias, const float* __restrict__ resid) {
    const u16* Bt = Bt0; void* C = C0;
    if (blockIdx.z == 1) { Bt = Bt1; C = C1; }
    else if (blockIdx.z == 2) { Bt = Bt2; C = C2; }

    __shared__ __align__(16) u16 Asm[BM * BK];
    __shared__ __align__(16) u16 Bsm[BN * BK];

    int tid = threadIdx.x;
    int lane = tid & 63, wave = tid >> 6;
    int l15 = lane & 15, quad = lane >> 4;
    int wm = wave & 1, wn = wave >> 1;
    long tm0 = (long)blockIdx.y * BM, tn0 = (long)blockIdx.x * BN;

    int srow = lane >> 3;
    int scol = (lane & 7) * 8;

    f32x4 acc[4][4] = {};

    for (int k0 = 0; k0 < K; k0 += BK) {
        __syncthreads();
        #pragma unroll
        for (int c = 0; c < 4; c++) {
            int chunk = wave * 4 + c;
            int row = chunk * 8 + srow;
            gload_lds16(&A[(tm0 + row) * (long)K + k0 + scol], &Asm[chunk * 512]);
            gload_lds16(&Bt[(tn0 + row) * (long)K + k0 + scol], &Bsm[chunk * 512]);
        }
        __syncthreads();
        #pragma unroll
        for (int ks = 0; ks < 2; ks++) {
            bf16x8 af[4], bfm[4];
            #pragma unroll
            for (int mt = 0; mt < 4; mt++)
                af[mt] = *(const bf16x8*)&Asm[(wm*64 + mt*16 + l15) * BK + ks*32 + quad*8];
            #pragma unroll
            for (int nt = 0; nt < 4; nt++)
                bfm[nt] = *(const bf16x8*)&Bsm[(wn*64 + nt*16 + l15) * BK + ks*32 + quad*8];
            #pragma unroll
            for (int mt = 0; mt < 4; mt++)
                #pragma unroll
                for (int nt = 0; nt < 4; nt++)
                    acc[mt][nt] = __builtin_amdgcn_mfma_f32_16x16x32_bf16(
                        af[mt], bfm[nt], acc[mt][nt], 0, 0, 0);
        }
    }

    #pragma unroll
    for (int mt = 0; mt < 4; mt++) {
        #pragma unroll
        for (int nt = 0; nt < 4; nt++) {
            #pragma unroll
            for (int i = 0; i < 4; i++) {
                long r = tm0 + wm*64 + mt*16 + quad*4 + i;
                long cn = tn0 + wn*64 + nt*16 + l15;
                long idx = r * N + cn;
                float val = acc[mt][nt][i];
                if (mode == 0) {
                    ((u16*)C)[idx] = f2bf(val);
                } else if (mode == 1) {
                    ((float*)C)[idx] = val + resid[idx];
                } else if (mode == 2) {
                    val += bias[cn];
                    ((u16*)C)[idx] = f2bf(gelu_fast(val));
                } else {
                    ((float*)C)[idx] = val + bias[cn] + resid[idx];
                }
            }
        }
    }
}

// ------------------------------------------------- GEMM 256^2 8-phase (QKV fused, W1)
// R16 kernel (KEEP): 8-phase counted-vmcnt schedule + T2 XOR swizzle
// (linear LDS dest, inverse-XOR'd global source, XOR'd read chunk —
// rule #21). R16 verified: ~120 us each (W1 ~573 TF), conflicts fixed.
#define BM2 256
#define BN2 256
#define BK2 64

__global__ __launch_bounds__(512, 2) void gemm8p(
    const u16* __restrict__ A, const u16* __restrict__ Bt,
    u16* __restrict__ C0, u16* __restrict__ C1, u16* __restrict__ C2,
    int N, int K, int mode, const float* __restrict__ bias) {
    __shared__ __align__(16) u16 lds[2 * 32768];   // 128 KB

    int tid = threadIdx.x;
    int lane = tid & 63, wave = tid >> 6;          // wave 0..7
    int l15 = lane & 15, quad = lane >> 4;
    int wm = wave & 1, wn = wave >> 1;             // M half, N quarter
    long tm0 = (long)blockIdx.y * BM2, tn0 = (long)blockIdx.x * BN2;
    int srow = lane >> 3;
    // T2 write-side: lane (srow, j) deposits global chunk j^srow so that
    // LDS slot (row, c') holds global chunk c'^(row&7).
    int scolw = ((lane & 7) ^ srow) * 8;
    // T2 read-side: chunk for (h, quad) at row with row&7 == l15&7.
    int sk = l15 & 7;
    int ca0 = ((quad) ^ sk) * 8;        // h=0 chunk offset (u16)
    int ca1 = ((4 + quad) ^ sk) * 8;    // h=1 chunk offset (u16)
    int steps = K >> 6;

    // stage one half-tile (half: 0=A-lo,1=A-hi,2=B-lo,3=B-hi) of K-tile kt.
    auto STAGE = [&](int kt, int half, int buf) {
        long kk = (long)kt * BK2;
        #pragma unroll
        for (int c = 0; c < 2; c++) {
            int chunk = wave * 2 + c;                       // 0..15
            int rloc = (half & 1) * 128 + chunk * 8 + srow; // row in tile
            const u16* g = (half < 2)
                ? &A [(tm0 + rloc) * (long)K + kk + scolw]
                : &Bt[(tn0 + rloc) * (long)K + kk + scolw];
            u16* l = &lds[buf * 32768 + (half >= 2 ? 16384 : 0)
                          + (half & 1) * 8192 + chunk * 512];
            gload_lds16(g, l);
        }
    };

    f32x4 acc[8][4] = {};
    bf16x8 af[4][2], bl[2][2], bh[2][2];

    // ---- prologue: tile0 (all 4 halves) -> buf0, B(1) -> buf1
    STAGE(0, 0, 0); STAGE(0, 1, 0); STAGE(0, 2, 0); STAGE(0, 3, 0);
    if (steps > 1) { STAGE(1, 2, 1); STAGE(1, 3, 1); }
    if (steps > 1) asm volatile("s_waitcnt vmcnt(4)" ::: "memory");
    else           asm volatile("s_waitcnt vmcnt(0)" ::: "memory");
    MBAR();

    for (int t = 0; t < steps; ++t) {
        int cur = t & 1;
        const u16* Ab = &lds[cur * 32768];
        const u16* Bb = &lds[cur * 32768 + 16384];
        bool pf1 = (t + 1 < steps), pf2 = (t + 2 < steps);

        // ---- ph1: read A-mlo + B-nlo; stage A-lo(t+1); MFMA Q(mlo,nlo)
        #pragma unroll
        for (int mt = 0; mt < 4; mt++) {
            int row = wm*128 + mt*16 + l15;
            af[mt][0] = *(const bf16x8*)&Ab[row * BK2 + ca0];
            af[mt][1] = *(const bf16x8*)&Ab[row * BK2 + ca1];
        }
        #pragma unroll
        for (int nt = 0; nt < 2; nt++) {
            int row = wn*64 + nt*16 + l15;
            bl[nt][0] = *(const bf16x8*)&Bb[row * BK2 + ca0];
            bl[nt][1] = *(const bf16x8*)&Bb[row * BK2 + ca1];
        }
        if (pf1) STAGE(t + 1, 0, cur ^ 1);
        MBAR();
        __builtin_amdgcn_s_setprio(1);
        #pragma unroll
        for (int mt = 0; mt < 4; mt++)
            #pragma unroll
            for (int nt = 0; nt < 2; nt++) {
                acc[mt][nt] = __builtin_amdgcn_mfma_f32_16x16x32_bf16(af[mt][0], bl[nt][0], acc[mt][nt], 0,0,0);
                acc[mt][nt] = __builtin_amdgcn_mfma_f32_16x16x32_bf16(af[mt][1], bl[nt][1], acc[mt][nt], 0,0,0);
            }
        __builtin_amdgcn_s_setprio(0);
        MBAR();

        // ---- ph2: read B-nhi; stage A-hi(t+1); MFMA Q(mlo,nhi)
        #pragma unroll
        for (int nt = 0; nt < 2; nt++) {
            int row = wn*64 + (2+nt)*16 + l15;
            bh[nt][0] = *(const bf16x8*)&Bb[row * BK2 + ca0];
            bh[nt][1] = *(const bf16x8*)&Bb[row * BK2 + ca1];
        }
        if (pf1) STAGE(t + 1, 1, cur ^ 1);
        MBAR();
        __builtin_amdgcn_s_setprio(1);
        #pragma unroll
        for (int mt = 0; mt < 4; mt++)
            #pragma unroll
            for (int nt = 0; nt < 2; nt++) {
                acc[mt][2+nt] = __builtin_amdgcn_mfma_f32_16x16x32_bf16(af[mt][0], bh[nt][0], acc[mt][2+nt], 0,0,0);
                acc[mt][2+nt] = __builtin_amdgcn_mfma_f32_16x16x32_bf16(af[mt][1], bh[nt][1], acc[mt][2+nt], 0,0,0);
            }
        __builtin_amdgcn_s_setprio(0);
        MBAR();

        // ---- ph3: read A-mhi (reuse af regs); stage B-lo(t+2); MFMA Q(mhi,nhi)
        #pragma unroll
        for (int mt = 0; mt < 4; mt++) {
            int row = wm*128 + 64 + mt*16 + l15;
            af[mt][0] = *(const bf16x8*)&Ab[row * BK2 + ca0];
            af[mt][1] = *(const bf16x8*)&Ab[row * BK2 + ca1];
        }
        if (pf2) STAGE(t + 2, 2, cur);
        MBAR();
        __builtin_amdgcn_s_setprio(1);
        #pragma unroll
        for (int mt = 0; mt < 4; mt++)
            #pragma unroll
            for (int nt = 0; nt < 2; nt++) {
                acc[4+mt][2+nt] = __builtin_amdgcn_mfma_f32_16x16x32_bf16(af[mt][0], bh[nt][0], acc[4+mt][2+nt], 0,0,0);
                acc[4+mt][2+nt] = __builtin_amdgcn_mfma_f32_16x16x32_bf16(af[mt][1], bh[nt][1], acc[4+mt][2+nt], 0,0,0);
            }
        __builtin_amdgcn_s_setprio(0);
        MBAR();

        // ---- ph4: stage B-hi(t+2); MFMA Q(mhi,nlo) (bl held from ph1); tile-end vmcnt
        if (pf2) STAGE(t + 2, 3, cur);
        MBAR();
        __builtin_amdgcn_s_setprio(1);
        #pragma unroll
        for (int mt = 0; mt < 4; mt++)
            #pragma unroll
            for (int nt = 0; nt < 2; nt++) {
                acc[4+mt][nt] = __builtin_amdgcn_mfma_f32_16x16x32_bf16(af[mt][0], bl[nt][0], acc[4+mt][nt], 0,0,0);
                acc[4+mt][nt] = __builtin_amdgcn_mfma_f32_16x16x32_bf16(af[mt][1], bl[nt][1], acc[4+mt][nt], 0,0,0);
            }
        __builtin_amdgcn_s_setprio(0);
        if (pf2) asm volatile("s_waitcnt vmcnt(4)" ::: "memory");
        else     asm volatile("s_waitcnt vmcnt(0)" ::: "memory");
        MBAR();
    }

    // ---- epilogue
    #pragma unroll
    for (int mt = 0; mt < 8; mt++) {
        #pragma unroll
        for (int nt = 0; nt < 4; nt++) {
            #pragma unroll
            for (int i = 0; i < 4; i++) {
                long r = tm0 + wm*128 + mt*16 + quad*4 + i;
                int cn = (int)tn0 + wn*64 + nt*16 + l15;
                float val = acc[mt][nt][i];
                if (mode == 0) {           // fused QKV: route to q/k/v slabs
                    int mi = cn >> 10;
                    int col = cn & 1023;
                    u16* base = (mi == 0) ? C0 : (mi == 1 ? C1 : C2);
                    base[r * 1024 + col] = f2bf(val);
                } else {                   // mode 2: bias + GELU -> bf16
                    val += bias[cn];
                    C0[r * (long)N + cn] = f2bf(gelu_fast(val));
                }
            }
        }
    }
}

// ------------------------------------------------- attention
// R17: ONE WAVE PER BLOCK (64 threads), grid (64 heads, 64 q-tiles),
// longest-tile-first (t = 63 - blockIdx.y, LPT order). R16 diagnosis:
// 4-wave blocks held LDS/wave slots until their LONGEST wave (24-32
// k-tiles) finished while the average wave had ~17 -> time-avg occupancy
// 15% vs 50% static. The kernel is zero-barrier wave-autonomous, so
// 1-wave blocks let the HW scheduler backfill freed slots dynamically.
// LDS 4.6 KB/block; launch_bounds(64,5) caps VGPR at 102 (92 fits) ->
// 20 waves/CU resident. Same math, same loads, byte-identical output.
// XCD locality: dispatch id % 8 = bh % 8 -> all blocks of a head on one XCD.
#define LDP 72   // P row stride in u16

__global__ __launch_bounds__(64, 5) void attn_kernel(
    const u16* __restrict__ Q, const u16* __restrict__ Kg, const u16* __restrict__ Vt,
    const int* __restrict__ mask, u16* __restrict__ O) {
    __shared__ __align__(16) u16 Pw[32 * LDP];     // 4.6 KB, wave-private
    int lane = threadIdx.x;                        // 0..63
    int l15 = lane & 15, quad = lane >> 4;
    int bh = blockIdx.x; int b = bh >> 4, h = bh & 15;
    int t = 63 - blockIdx.y;           // q-tile, big-first (LPT)
    long tokBase = (long)b * S_;
    const float SCL = 0.125f * 1.4426950408889634f;  // exp2 domain
    const float MMAX = 20.0f;                        // fixed softmax shift

    const bf16x8 ones = {16256,16256,16256,16256,16256,16256,16256,16256}; // bf16 1.0
    const int* mb = mask + b * S_;

    int q0 = t * 32;

    bf16x8 aq[2][2];
    #pragma unroll
    for (int mt = 0; mt < 2; mt++) {
        const u16* qptr = Q + (tokBase + q0 + mt*16 + l15) * D_ + h * 64;
        aq[mt][0] = *(const bf16x8*)(qptr + quad * 8);
        aq[mt][1] = *(const bf16x8*)(qptr + 32 + quad * 8);
    }

    f32x4 o[2][4] = {};
    f32x4 lacc[2] = {};
    int ktiles = t / 2 + 1;

    // prefetch kb for kt=0
    bf16x8 kb[4][2];
    #pragma unroll
    for (int nt = 0; nt < 4; nt++) {
        const u16* kp = Kg + (tokBase + nt*16 + l15) * D_ + h * 64;
        kb[nt][0] = *(const bf16x8*)(kp + quad * 8);
        kb[nt][1] = *(const bf16x8*)(kp + 32 + quad * 8);
    }

    for (int kt = 0; kt < ktiles; kt++) {
        int k0 = kt * 64;
        bf16x8 vb[4][2];
        #pragma unroll
        for (int d = 0; d < 4; d++) {
            const u16* vp = Vt + ((long)bh * 64 + d*16 + l15) * S_ + k0;
            vb[d][0] = *(const bf16x8*)(vp + quad * 8);
            vb[d][1] = *(const bf16x8*)(vp + 32 + quad * 8);
        }

        f32x4 s[2][4] = {};
        #pragma unroll
        for (int nt = 0; nt < 4; nt++) {
            s[0][nt] = __builtin_amdgcn_mfma_f32_16x16x32_bf16(aq[0][0], kb[nt][0], s[0][nt], 0,0,0);
            s[0][nt] = __builtin_amdgcn_mfma_f32_16x16x32_bf16(aq[0][1], kb[nt][1], s[0][nt], 0,0,0);
            s[1][nt] = __builtin_amdgcn_mfma_f32_16x16x32_bf16(aq[1][0], kb[nt][0], s[1][nt], 0,0,0);
            s[1][nt] = __builtin_amdgcn_mfma_f32_16x16x32_bf16(aq[1][1], kb[nt][1], s[1][nt], 0,0,0);
        }

        // prefetch kb(t+1) NOW — latency hides under the softmax below.
        int k1 = (kt + 1 < ktiles) ? k0 + 64 : k0;
        bf16x8 kbn[4][2];
        #pragma unroll
        for (int nt = 0; nt < 4; nt++) {
            const u16* kp = Kg + (tokBase + k1 + nt*16 + l15) * D_ + h * 64;
            kbn[nt][0] = *(const bf16x8*)(kp + quad * 8);
            kbn[nt][1] = *(const bf16x8*)(kp + 32 + quad * 8);
        }

        int mk = 0;
        #pragma unroll
        for (int nt = 0; nt < 4; nt++)
            if (mb[k0 + nt*16 + l15] != 0) mk |= (1 << nt);

        #pragma unroll
        for (int mt = 0; mt < 2; mt++) {
            #pragma unroll
            for (int i = 0; i < 4; i++) {
                int qq = q0 + mt*16 + quad*4 + i;
                #pragma unroll
                for (int nt = 0; nt < 4; nt++) {
                    int kc = k0 + nt*16 + l15;
                    float p = exp2f(fmaf(s[mt][nt][i], SCL, -MMAX));
                    p = (kc <= qq && ((mk >> nt) & 1)) ? p : 0.f;
                    Pw[(mt*16 + quad*4 + i) * LDP + nt*16 + l15] = f2bf(p);
                }
            }
        }
        // same-wave P write -> read ordering (P is wave-private; LDS only —
        // the kbn global loads above stay in flight, they are vmcnt).
        asm volatile("s_waitcnt lgkmcnt(0)" ::: "memory");

        #pragma unroll
        for (int hv = 0; hv < 2; hv++) {
            bf16x8 ap0 = *(const bf16x8*)&Pw[l15 * LDP + hv*32 + quad*8];
            bf16x8 ap1 = *(const bf16x8*)&Pw[(16 + l15) * LDP + hv*32 + quad*8];
            #pragma unroll
            for (int d = 0; d < 4; d++) {
                o[0][d] = __builtin_amdgcn_mfma_f32_16x16x32_bf16(ap0, vb[d][hv], o[0][d], 0,0,0);
                o[1][d] = __builtin_amdgcn_mfma_f32_16x16x32_bf16(ap1, vb[d][hv], o[1][d], 0,0,0);
            }
            lacc[0] = __builtin_amdgcn_mfma_f32_16x16x32_bf16(ap0, ones, lacc[0], 0,0,0);
            lacc[1] = __builtin_amdgcn_mfma_f32_16x16x32_bf16(ap1, ones, lacc[1], 0,0,0);
        }

        // rotate prefetched K into place
        #pragma unroll
        for (int nt = 0; nt < 4; nt++) {
            kb[nt][0] = kbn[nt][0];
            kb[nt][1] = kbn[nt][1];
        }
    }

    #pragma unroll
    for (int mt = 0; mt < 2; mt++) {
        #pragma unroll
        for (int i = 0; i < 4; i++) {
            float inv = 1.f / lacc[mt][i];
            long r = tokBase + q0 + mt*16 + quad*4 + i;
            #pragma unroll
            for (int d = 0; d < 4; d++)
                O[r * D_ + h*64 + d*16 + l15] = f2bf(o[mt][d][i] * inv);
        }
    }
}

// ------------------------------------------------- launch
extern "C" void kernel_launch(void* const* d_in, const int* in_sizes, int n_in,
                              void* d_out, int out_size, void* d_ws, size_t ws_size,
                              hipStream_t stream) {
    const float* x    = (const float*)d_in[0];
    const int*   am   = (const int*)d_in[1];
    const float* ln1a = (const float*)d_in[2];
    const float* ln1b = (const float*)d_in[3];
    const float* ln2a = (const float*)d_in[4];
    const float* ln2b = (const float*)d_in[5];
    const float* wq   = (const float*)d_in[6];
    const float* wk   = (const float*)d_in[7];
    const float* wv   = (const float*)d_in[8];
    const float* wo   = (const float*)d_in[9];
    const float* w1   = (const float*)d_in[10];
    const float* b1   = (const float*)d_in[11];
    const float* w2   = (const float*)d_in[12];
    const float* b2   = (const float*)d_in[13];
    float* out = (float*)d_out;

    // Workspace: 72 MB, liveness-overlapped 16MB slots.
    char* ws = (char*)d_ws;
    const size_t MB16 = (size_t)16 * 1024 * 1024;
    u16* y1      = (u16*)(ws + 0 * MB16);
    u16* q       = (u16*)(ws + 1 * MB16);
    u16* k       = (u16*)(ws + 2 * MB16);
    u16* v       = (u16*)(ws + 3 * MB16);
    u16* wqt     = (u16*)(ws + 4 * MB16 + 0 * (size_t)D_ * D_ * 2);
    u16* wkt     = (u16*)(ws + 4 * MB16 + 1 * (size_t)D_ * D_ * 2);
    u16* wvt     = (u16*)(ws + 4 * MB16 + 2 * (size_t)D_ * D_ * 2);
    u16* wot     = (u16*)(ws + 4 * MB16 + 3 * (size_t)D_ * D_ * 2);
    u16* y2      = y1;
    u16* w1t     = q;
    u16* w2t     = q + (size_t)D_ * DFF;
    u16* h_full  = k;
    u16* ctx     = v;
    u16*   vt  = (u16*)d_out;                // d_out scratch; dead after attn
    float* x1f = out;

    dim3 tb(32, 8);
    transpose_f2b4<<<dim3(D_/32, D_/32, 4), tb, 0, stream>>>(
        wq, wk, wv, wo, wqt, wkt, wvt, wot, D_, D_);

    ln_kernel<<<NT, 256, 0, stream>>>(x, ln1a, ln1b, y1);

    // fused QKV: wqt/wkt/wvt are contiguous -> one [3072][1024] B matrix
    gemm8p<<<dim3(3*D_/BN2, NT/BM2), 512, 0, stream>>>(
        y1, wqt, q, k, v, 3*D_, D_, 0, nullptr);

    transpose_v<<<dim3(S_/32, 2, B_*H_), tb, 0, stream>>>(v, vt);

    attn_kernel<<<dim3(B_*H_, 64), 64, 0, stream>>>(q, k, vt, am, ctx);

    gemm_bt<<<dim3(D_/BN, NT/BM, 1), 256, 0, stream>>>(
        ctx, wot, wot, wot, x1f, x1f, x1f, NT, D_, D_, 1, nullptr, x);

    transpose_f2b<<<dim3(DFF/32, D_/32), tb, 0, stream>>>(w1, w1t, D_, DFF);
    transpose_f2b<<<dim3(D_/32, DFF/32), tb, 0, stream>>>(w2, w2t, DFF, D_);

    ln_kernel<<<NT, 256, 0, stream>>>(x1f, ln2a, ln2b, y2);

    gemm8p<<<dim3(DFF/BN2, NT/BM2), 512, 0, stream>>>(
        y2, w1t, h_full, h_full, h_full, DFF, D_, 2, b1);
    gemm_bt<<<dim3(D_/BN, NT/BM, 1), 256, 0, stream>>>(
        h_full, w2t, w2t, w2t, out, out, out, NT, D_, DFF, 3, b2, x1f);
}

// Round 10
// 630.081 us; speedup vs baseline: 1.3200x; 1.3200x over previous
//
#include <hip/hip_runtime.h>
#include <math.h>

typedef unsigned short u16;
typedef unsigned int u32;
typedef __attribute__((ext_vector_type(4))) unsigned short u16x4;
typedef __attribute__((ext_vector_type(8))) short bf16x8;
typedef __attribute__((ext_vector_type(4))) float f32x4;

#define B_ 4
#define S_ 2048
#define D_ 1024
#define H_ 16
#define NT (B_*S_)
#define DFF 4096

static __device__ __forceinline__ float bf2f(u16 u) {
    return __uint_as_float(((u32)u) << 16);
}
static __device__ __forceinline__ u16 f2bf(float f) {
    u32 u = __float_as_uint(f);
    u32 r = (u + 0x7fffu + ((u >> 16) & 1u)) >> 16;
    return (u16)r;
}
// async 16B/lane global->LDS (LDS dest = wave-uniform base + lane*16)
static __device__ __forceinline__ void gload_lds16(const void* g, void* l) {
    __builtin_amdgcn_global_load_lds(
        (const __attribute__((address_space(1))) void*)g,
        (__attribute__((address_space(3))) void*)l, 16, 0, 0);
}
// tanh-form GELU via hw exp2 (validated R14: passed absmax 0.0625).
static __device__ __forceinline__ float gelu_fast(float x) {
    float x2 = x * x;
    float u = x * fmaf(0.044715f, x2, 1.0f);
    float e = exp2f(2.3022079f * u);
    float r = __builtin_amdgcn_rcpf(e + 1.0f);
    return x - x * r;
}

// raw barrier (no implicit vmcnt(0) drain, unlike __syncthreads) with
// compiler memory fences so C++ LDS reads can't be hoisted across it.
#define MBAR() do { asm volatile("" ::: "memory"); \
                    __builtin_amdgcn_s_barrier(); \
                    asm volatile("" ::: "memory"); } while (0)

// ------------------------------------------------- transpose fp32 -> bf16
__global__ void transpose_f2b4(const float* __restrict__ s0, const float* __restrict__ s1,
                               const float* __restrict__ s2, const float* __restrict__ s3,
                               u16* __restrict__ d0, u16* __restrict__ d1,
                               u16* __restrict__ d2, u16* __restrict__ d3,
                               int R, int C) {
    const float* in = s0; u16* out = d0;
    if (blockIdx.z == 1) { in = s1; out = d1; }
    else if (blockIdx.z == 2) { in = s2; out = d2; }
    else if (blockIdx.z == 3) { in = s3; out = d3; }
    __shared__ float t[32][33];
    int c0 = blockIdx.x * 32, r0 = blockIdx.y * 32;
    int x = threadIdx.x, y = threadIdx.y;
    #pragma unroll
    for (int i = 0; i < 4; i++)
        t[y + i*8][x] = in[(long)(r0 + y + i*8) * C + c0 + x];
    __syncthreads();
    #pragma unroll
    for (int i = 0; i < 4; i++)
        out[(long)(c0 + y + i*8) * R + r0 + x] = f2bf(t[x][y + i*8]);
}

__global__ void transpose_f2b(const float* __restrict__ in, u16* __restrict__ out,
                              int R, int C) {
    __shared__ float t[32][33];
    int c0 = blockIdx.x * 32, r0 = blockIdx.y * 32;
    int x = threadIdx.x, y = threadIdx.y;
    #pragma unroll
    for (int i = 0; i < 4; i++)
        t[y + i*8][x] = in[(long)(r0 + y + i*8) * C + c0 + x];
    __syncthreads();
    #pragma unroll
    for (int i = 0; i < 4; i++)
        out[(long)(c0 + y + i*8) * R + r0 + x] = f2bf(t[x][y + i*8]);
}

// V bf16 [B*S][D] -> Vt bf16 [B*H][64][S]. grid (S/32, 2, B*H), block (32,8)
__global__ void transpose_v(const u16* __restrict__ V, u16* __restrict__ Vt) {
    __shared__ u16 t[32][33];
    int z = blockIdx.z; int b = z >> 4, h = z & 15;
    int s0 = blockIdx.x * 32, d0 = blockIdx.y * 32;
    int x = threadIdx.x, y = threadIdx.y;
    const u16* in = V + ((long)b * S_ + s0) * D_ + h * 64 + d0;
    #pragma unroll
    for (int i = 0; i < 4; i++)
        t[y + i*8][x] = in[(long)(y + i*8) * D_ + x];
    __syncthreads();
    u16* out = Vt + ((long)z * 64 + d0) * S_ + s0;
    #pragma unroll
    for (int i = 0; i < 4; i++)
        out[(long)(y + i*8) * S_ + x] = t[x][y + i*8];
}

// ------------------------------------------------- layernorm (fp32 in, bf16 out)
__global__ __launch_bounds__(256) void ln_kernel(
    const float* __restrict__ X, const float* __restrict__ alpha,
    const float* __restrict__ beta, u16* __restrict__ Y) {
    int row = blockIdx.x, tid = threadIdx.x;
    float4 xv = ((const float4*)(X + (long)row * D_))[tid];
    float v[4] = {xv.x, xv.y, xv.z, xv.w};
    float s = 0.f, ss = 0.f;
    #pragma unroll
    for (int i = 0; i < 4; i++) { s += v[i]; ss += v[i]*v[i]; }
    #pragma unroll
    for (int off = 32; off >= 1; off >>= 1) {
        s += __shfl_xor(s, off);
        ss += __shfl_xor(ss, off);
    }
    __shared__ float red[8];
    __shared__ float stats[2];
    int w = tid >> 6;
    if ((tid & 63) == 0) { red[w] = s; red[4 + w] = ss; }
    __syncthreads();
    if (tid == 0) {
        float S = red[0] + red[1] + red[2] + red[3];
        float SS = red[4] + red[5] + red[6] + red[7];
        float mean = S * (1.f / D_);
        float var = SS * (1.f / D_) - mean * mean;
        stats[0] = mean; stats[1] = rsqrtf(var + 1e-5f);
    }
    __syncthreads();
    float mean = stats[0], rstd = stats[1];
    float4 av = ((const float4*)alpha)[tid];
    float4 bv = ((const float4*)beta)[tid];
    u16x4 o;
    o[0] = f2bf((v[0] - mean) * rstd * av.x + bv.x);
    o[1] = f2bf((v[1] - mean) * rstd * av.y + bv.y);
    o[2] = f2bf((v[2] - mean) * rstd * av.z + bv.z);
    o[3] = f2bf((v[3] - mean) * rstd * av.w + bv.w);
    *(u16x4*)(Y + (long)row * D_ + tid * 4) = o;
}

// ------------------------------------------------- GEMM 128^2 (Wo, W2)
// BASELINE m97 recipe, untouched. N=1024 shapes stay here.
#define BM 128
#define BN 128
#define BK 64

__global__ __launch_bounds__(256, 3) void gemm_bt(
    const u16* __restrict__ A,
    const u16* __restrict__ Bt0, const u16* __restrict__ Bt1, const u16* __restrict__ Bt2,
    void* __restrict__ C0, void* __restrict__ C1, void* __restrict__ C2,
    int M, int N, int K, int mode,
    const float* __restrict__ bias, const float* __restrict__ resid) {
    const u16* Bt = Bt0; void* C = C0;
    if (blockIdx.z == 1) { Bt = Bt1; C = C1; }
    else if (blockIdx.z == 2) { Bt = Bt2; C = C2; }

    __shared__ __align__(16) u16 Asm[BM * BK];
    __shared__ __align__(16) u16 Bsm[BN * BK];

    int tid = threadIdx.x;
    int lane = tid & 63, wave = tid >> 6;
    int l15 = lane & 15, quad = lane >> 4;
    int wm = wave & 1, wn = wave >> 1;
    long tm0 = (long)blockIdx.y * BM, tn0 = (long)blockIdx.x * BN;

    int srow = lane >> 3;
    int scol = (lane & 7) * 8;

    f32x4 acc[4][4] = {};

    for (int k0 = 0; k0 < K; k0 += BK) {
        __syncthreads();
        #pragma unroll
        for (int c = 0; c < 4; c++) {
            int chunk = wave * 4 + c;
            int row = chunk * 8 + srow;
            gload_lds16(&A[(tm0 + row) * (long)K + k0 + scol], &Asm[chunk * 512]);
            gload_lds16(&Bt[(tn0 + row) * (long)K + k0 + scol], &Bsm[chunk * 512]);
        }
        __syncthreads();
        #pragma unroll
        for (int ks = 0; ks < 2; ks++) {
            bf16x8 af[4], bfm[4];
            #pragma unroll
            for (int mt = 0; mt < 4; mt++)
                af[mt] = *(const bf16x8*)&Asm[(wm*64 + mt*16 + l15) * BK + ks*32 + quad*8];
            #pragma unroll
            for (int nt = 0; nt < 4; nt++)
                bfm[nt] = *(const bf16x8*)&Bsm[(wn*64 + nt*16 + l15) * BK + ks*32 + quad*8];
            #pragma unroll
            for (int mt = 0; mt < 4; mt++)
                #pragma unroll
                for (int nt = 0; nt < 4; nt++)
                    acc[mt][nt] = __builtin_amdgcn_mfma_f32_16x16x32_bf16(
                        af[mt], bfm[nt], acc[mt][nt], 0, 0, 0);
        }
    }

    #pragma unroll
    for (int mt = 0; mt < 4; mt++) {
        #pragma unroll
        for (int nt = 0; nt < 4; nt++) {
            #pragma unroll
            for (int i = 0; i < 4; i++) {
                long r = tm0 + wm*64 + mt*16 + quad*4 + i;
                long cn = tn0 + wn*64 + nt*16 + l15;
                long idx = r * N + cn;
                float val = acc[mt][nt][i];
                if (mode == 0) {
                    ((u16*)C)[idx] = f2bf(val);
                } else if (mode == 1) {
                    ((float*)C)[idx] = val + resid[idx];
                } else if (mode == 2) {
                    val += bias[cn];
                    ((u16*)C)[idx] = f2bf(gelu_fast(val));
                } else {
                    ((float*)C)[idx] = val + bias[cn] + resid[idx];
                }
            }
        }
    }
}

// ------------------------------------------------- GEMM 256^2 8-phase (QKV fused, W1)
// R16 kernel (KEEP): 8-phase counted-vmcnt schedule + T2 XOR swizzle
// (linear LDS dest, inverse-XOR'd global source, XOR'd read chunk —
// rule #21). R16 verified: ~120 us each (W1 ~573 TF), conflicts fixed.
#define BM2 256
#define BN2 256
#define BK2 64

__global__ __launch_bounds__(512, 2) void gemm8p(
    const u16* __restrict__ A, const u16* __restrict__ Bt,
    u16* __restrict__ C0, u16* __restrict__ C1, u16* __restrict__ C2,
    int N, int K, int mode, const float* __restrict__ bias) {
    __shared__ __align__(16) u16 lds[2 * 32768];   // 128 KB

    int tid = threadIdx.x;
    int lane = tid & 63, wave = tid >> 6;          // wave 0..7
    int l15 = lane & 15, quad = lane >> 4;
    int wm = wave & 1, wn = wave >> 1;             // M half, N quarter
    long tm0 = (long)blockIdx.y * BM2, tn0 = (long)blockIdx.x * BN2;
    int srow = lane >> 3;
    // T2 write-side: lane (srow, j) deposits global chunk j^srow so that
    // LDS slot (row, c') holds global chunk c'^(row&7).
    int scolw = ((lane & 7) ^ srow) * 8;
    // T2 read-side: chunk for (h, quad) at row with row&7 == l15&7.
    int sk = l15 & 7;
    int ca0 = ((quad) ^ sk) * 8;        // h=0 chunk offset (u16)
    int ca1 = ((4 + quad) ^ sk) * 8;    // h=1 chunk offset (u16)
    int steps = K >> 6;

    // stage one half-tile (half: 0=A-lo,1=A-hi,2=B-lo,3=B-hi) of K-tile kt.
    auto STAGE = [&](int kt, int half, int buf) {
        long kk = (long)kt * BK2;
        #pragma unroll
        for (int c = 0; c < 2; c++) {
            int chunk = wave * 2 + c;                       // 0..15
            int rloc = (half & 1) * 128 + chunk * 8 + srow; // row in tile
            const u16* g = (half < 2)
                ? &A [(tm0 + rloc) * (long)K + kk + scolw]
                : &Bt[(tn0 + rloc) * (long)K + kk + scolw];
            u16* l = &lds[buf * 32768 + (half >= 2 ? 16384 : 0)
                          + (half & 1) * 8192 + chunk * 512];
            gload_lds16(g, l);
        }
    };

    f32x4 acc[8][4] = {};
    bf16x8 af[4][2], bl[2][2], bh[2][2];

    // ---- prologue: tile0 (all 4 halves) -> buf0, B(1) -> buf1
    STAGE(0, 0, 0); STAGE(0, 1, 0); STAGE(0, 2, 0); STAGE(0, 3, 0);
    if (steps > 1) { STAGE(1, 2, 1); STAGE(1, 3, 1); }
    if (steps > 1) asm volatile("s_waitcnt vmcnt(4)" ::: "memory");
    else           asm volatile("s_waitcnt vmcnt(0)" ::: "memory");
    MBAR();

    for (int t = 0; t < steps; ++t) {
        int cur = t & 1;
        const u16* Ab = &lds[cur * 32768];
        const u16* Bb = &lds[cur * 32768 + 16384];
        bool pf1 = (t + 1 < steps), pf2 = (t + 2 < steps);

        // ---- ph1: read A-mlo + B-nlo; stage A-lo(t+1); MFMA Q(mlo,nlo)
        #pragma unroll
        for (int mt = 0; mt < 4; mt++) {
            int row = wm*128 + mt*16 + l15;
            af[mt][0] = *(const bf16x8*)&Ab[row * BK2 + ca0];
            af[mt][1] = *(const bf16x8*)&Ab[row * BK2 + ca1];
        }
        #pragma unroll
        for (int nt = 0; nt < 2; nt++) {
            int row = wn*64 + nt*16 + l15;
            bl[nt][0] = *(const bf16x8*)&Bb[row * BK2 + ca0];
            bl[nt][1] = *(const bf16x8*)&Bb[row * BK2 + ca1];
        }
        if (pf1) STAGE(t + 1, 0, cur ^ 1);
        MBAR();
        __builtin_amdgcn_s_setprio(1);
        #pragma unroll
        for (int mt = 0; mt < 4; mt++)
            #pragma unroll
            for (int nt = 0; nt < 2; nt++) {
                acc[mt][nt] = __builtin_amdgcn_mfma_f32_16x16x32_bf16(af[mt][0], bl[nt][0], acc[mt][nt], 0,0,0);
                acc[mt][nt] = __builtin_amdgcn_mfma_f32_16x16x32_bf16(af[mt][1], bl[nt][1], acc[mt][nt], 0,0,0);
            }
        __builtin_amdgcn_s_setprio(0);
        MBAR();

        // ---- ph2: read B-nhi; stage A-hi(t+1); MFMA Q(mlo,nhi)
        #pragma unroll
        for (int nt = 0; nt < 2; nt++) {
            int row = wn*64 + (2+nt)*16 + l15;
            bh[nt][0] = *(const bf16x8*)&Bb[row * BK2 + ca0];
            bh[nt][1] = *(const bf16x8*)&Bb[row * BK2 + ca1];
        }
        if (pf1) STAGE(t + 1, 1, cur ^ 1);
        MBAR();
        __builtin_amdgcn_s_setprio(1);
        #pragma unroll
        for (int mt = 0; mt < 4; mt++)
            #pragma unroll
            for (int nt = 0; nt < 2; nt++) {
                acc[mt][2+nt] = __builtin_amdgcn_mfma_f32_16x16x32_bf16(af[mt][0], bh[nt][0], acc[mt][2+nt], 0,0,0);
                acc[mt][2+nt] = __builtin_amdgcn_mfma_f32_16x16x32_bf16(af[mt][1], bh[nt][1], acc[mt][2+nt], 0,0,0);
            }
        __builtin_amdgcn_s_setprio(0);
        MBAR();

        // ---- ph3: read A-mhi (reuse af regs); stage B-lo(t+2); MFMA Q(mhi,nhi)
        #pragma unroll
        for (int mt = 0; mt < 4; mt++) {
            int row = wm*128 + 64 + mt*16 + l15;
            af[mt][0] = *(const bf16x8*)&Ab[row * BK2 + ca0];
            af[mt][1] = *(const bf16x8*)&Ab[row * BK2 + ca1];
        }
        if (pf2) STAGE(t + 2, 2, cur);
        MBAR();
        __builtin_amdgcn_s_setprio(1);
        #pragma unroll
        for (int mt = 0; mt < 4; mt++)
            #pragma unroll
            for (int nt = 0; nt < 2; nt++) {
                acc[4+mt][2+nt] = __builtin_amdgcn_mfma_f32_16x16x32_bf16(af[mt][0], bh[nt][0], acc[4+mt][2+nt], 0,0,0);
                acc[4+mt][2+nt] = __builtin_amdgcn_mfma_f32_16x16x32_bf16(af[mt][1], bh[nt][1], acc[4+mt][2+nt], 0,0,0);
            }
        __builtin_amdgcn_s_setprio(0);
        MBAR();

        // ---- ph4: stage B-hi(t+2); MFMA Q(mhi,nlo) (bl held from ph1); tile-end vmcnt
        if (pf2) STAGE(t + 2, 3, cur);
        MBAR();
        __builtin_amdgcn_s_setprio(1);
        #pragma unroll
        for (int mt = 0; mt < 4; mt++)
            #pragma unroll
            for (int nt = 0; nt < 2; nt++) {
                acc[4+mt][nt] = __builtin_amdgcn_mfma_f32_16x16x32_bf16(af[mt][0], bl[nt][0], acc[4+mt][nt], 0,0,0);
                acc[4+mt][nt] = __builtin_amdgcn_mfma_f32_16x16x32_bf16(af[mt][1], bl[nt][1], acc[4+mt][nt], 0,0,0);
            }
        __builtin_amdgcn_s_setprio(0);
        if (pf2) asm volatile("s_waitcnt vmcnt(4)" ::: "memory");
        else     asm volatile("s_waitcnt vmcnt(0)" ::: "memory");
        MBAR();
    }

    // ---- epilogue
    #pragma unroll
    for (int mt = 0; mt < 8; mt++) {
        #pragma unroll
        for (int nt = 0; nt < 4; nt++) {
            #pragma unroll
            for (int i = 0; i < 4; i++) {
                long r = tm0 + wm*128 + mt*16 + quad*4 + i;
                int cn = (int)tn0 + wn*64 + nt*16 + l15;
                float val = acc[mt][nt][i];
                if (mode == 0) {           // fused QKV: route to q/k/v slabs
                    int mi = cn >> 10;
                    int col = cn & 1023;
                    u16* base = (mi == 0) ? C0 : (mi == 1 ? C1 : C2);
                    base[r * 1024 + col] = f2bf(val);
                } else {                   // mode 2: bias + GELU -> bf16
                    val += bias[cn];
                    C0[r * (long)N + cn] = f2bf(gelu_fast(val));
                }
            }
        }
    }
}

// ------------------------------------------------- attention
// R18: 2-wave blocks (128 thr), grid (64, 16); wave j = 2*blockIdx.y+wave
// handles the BALANCED pair (j, 63-j): ktiles sum = 33-34 for EVERY wave,
// so no intra-block drag (R16's limiter: 4-wave blocks waited on their
// longest wave, time-avg occupancy 15% vs 50% static). 1024 blocks of
// 9.2 KB LDS; bounds(128,2) caps VGPR at 256 (R16 body ran 92; R17's
// aggressive (64,5) cap caused a 48-VGPR spill catastrophe — never cap
// below ~128 on this body). At 92 VGPR: 5 waves/SIMD -> 10 blocks/CU.
#define LDP 72   // P row stride in u16

__global__ __launch_bounds__(128, 2) void attn_kernel(
    const u16* __restrict__ Q, const u16* __restrict__ Kg, const u16* __restrict__ Vt,
    const int* __restrict__ mask, u16* __restrict__ O) {
    __shared__ __align__(16) u16 Psm[2][32 * LDP];   // 9.2 KB
    int tid = threadIdx.x;
    int lane = tid & 63, wave = tid >> 6;            // 0..1
    int l15 = lane & 15, quad = lane >> 4;
    int bh = blockIdx.x; int b = bh >> 4, h = bh & 15;
    int j = blockIdx.y * 2 + wave;     // pair index 0..31
    long tokBase = (long)b * S_;
    const float SCL = 0.125f * 1.4426950408889634f;  // exp2 domain
    const float MMAX = 20.0f;                        // fixed softmax shift

    const bf16x8 ones = {16256,16256,16256,16256,16256,16256,16256,16256}; // bf16 1.0
    u16* Pw = Psm[wave];
    const int* mb = mask + b * S_;

    #pragma unroll
    for (int half = 0; half < 2; half++) {
        int t = half ? (63 - j) : j;   // q-tile index 0..63
        int q0 = t * 32;

        bf16x8 aq[2][2];
        #pragma unroll
        for (int mt = 0; mt < 2; mt++) {
            const u16* qptr = Q + (tokBase + q0 + mt*16 + l15) * D_ + h * 64;
            aq[mt][0] = *(const bf16x8*)(qptr + quad * 8);
            aq[mt][1] = *(const bf16x8*)(qptr + 32 + quad * 8);
        }

        f32x4 o[2][4] = {};
        f32x4 lacc[2] = {};
        int ktiles = t / 2 + 1;

        // prefetch kb for kt=0
        bf16x8 kb[4][2];
        #pragma unroll
        for (int nt = 0; nt < 4; nt++) {
            const u16* kp = Kg + (tokBase + nt*16 + l15) * D_ + h * 64;
            kb[nt][0] = *(const bf16x8*)(kp + quad * 8);
            kb[nt][1] = *(const bf16x8*)(kp + 32 + quad * 8);
        }

        for (int kt = 0; kt < ktiles; kt++) {
            int k0 = kt * 64;
            bf16x8 vb[4][2];
            #pragma unroll
            for (int d = 0; d < 4; d++) {
                const u16* vp = Vt + ((long)bh * 64 + d*16 + l15) * S_ + k0;
                vb[d][0] = *(const bf16x8*)(vp + quad * 8);
                vb[d][1] = *(const bf16x8*)(vp + 32 + quad * 8);
            }

            f32x4 s[2][4] = {};
            #pragma unroll
            for (int nt = 0; nt < 4; nt++) {
                s[0][nt] = __builtin_amdgcn_mfma_f32_16x16x32_bf16(aq[0][0], kb[nt][0], s[0][nt], 0,0,0);
                s[0][nt] = __builtin_amdgcn_mfma_f32_16x16x32_bf16(aq[0][1], kb[nt][1], s[0][nt], 0,0,0);
                s[1][nt] = __builtin_amdgcn_mfma_f32_16x16x32_bf16(aq[1][0], kb[nt][0], s[1][nt], 0,0,0);
                s[1][nt] = __builtin_amdgcn_mfma_f32_16x16x32_bf16(aq[1][1], kb[nt][1], s[1][nt], 0,0,0);
            }

            // prefetch kb(t+1) NOW — latency hides under the softmax below.
            int k1 = (kt + 1 < ktiles) ? k0 + 64 : k0;
            bf16x8 kbn[4][2];
            #pragma unroll
            for (int nt = 0; nt < 4; nt++) {
                const u16* kp = Kg + (tokBase + k1 + nt*16 + l15) * D_ + h * 64;
                kbn[nt][0] = *(const bf16x8*)(kp + quad * 8);
                kbn[nt][1] = *(const bf16x8*)(kp + 32 + quad * 8);
            }

            int mk = 0;
            #pragma unroll
            for (int nt = 0; nt < 4; nt++)
                if (mb[k0 + nt*16 + l15] != 0) mk |= (1 << nt);

            #pragma unroll
            for (int mt = 0; mt < 2; mt++) {
                #pragma unroll
                for (int i = 0; i < 4; i++) {
                    int qq = q0 + mt*16 + quad*4 + i;
                    #pragma unroll
                    for (int nt = 0; nt < 4; nt++) {
                        int kc = k0 + nt*16 + l15;
                        float p = exp2f(fmaf(s[mt][nt][i], SCL, -MMAX));
                        p = (kc <= qq && ((mk >> nt) & 1)) ? p : 0.f;
                        Pw[(mt*16 + quad*4 + i) * LDP + nt*16 + l15] = f2bf(p);
                    }
                }
            }
            // same-wave P write -> read ordering (P is wave-private; LDS only —
            // the kbn global loads above stay in flight, they are vmcnt).
            asm volatile("s_waitcnt lgkmcnt(0)" ::: "memory");

            #pragma unroll
            for (int hv = 0; hv < 2; hv++) {
                bf16x8 ap0 = *(const bf16x8*)&Pw[l15 * LDP + hv*32 + quad*8];
                bf16x8 ap1 = *(const bf16x8*)&Pw[(16 + l15) * LDP + hv*32 + quad*8];
                #pragma unroll
                for (int d = 0; d < 4; d++) {
                    o[0][d] = __builtin_amdgcn_mfma_f32_16x16x32_bf16(ap0, vb[d][hv], o[0][d], 0,0,0);
                    o[1][d] = __builtin_amdgcn_mfma_f32_16x16x32_bf16(ap1, vb[d][hv], o[1][d], 0,0,0);
                }
                lacc[0] = __builtin_amdgcn_mfma_f32_16x16x32_bf16(ap0, ones, lacc[0], 0,0,0);
                lacc[1] = __builtin_amdgcn_mfma_f32_16x16x32_bf16(ap1, ones, lacc[1], 0,0,0);
            }

            // rotate prefetched K into place
            #pragma unroll
            for (int nt = 0; nt < 4; nt++) {
                kb[nt][0] = kbn[nt][0];
                kb[nt][1] = kbn[nt][1];
            }
        }

        #pragma unroll
        for (int mt = 0; mt < 2; mt++) {
            #pragma unroll
            for (int i = 0; i < 4; i++) {
                float inv = 1.f / lacc[mt][i];
                long r = tokBase + q0 + mt*16 + quad*4 + i;
                #pragma unroll
                for (int d = 0; d < 4; d++)
                    O[r * D_ + h*64 + d*16 + l15] = f2bf(o[mt][d][i] * inv);
            }
        }
    }
}

// ------------------------------------------------- launch
extern "C" void kernel_launch(void* const* d_in, const int* in_sizes, int n_in,
                              void* d_out, int out_size, void* d_ws, size_t ws_size,
                              hipStream_t stream) {
    const float* x    = (const float*)d_in[0];
    const int*   am   = (const int*)d_in[1];
    const float* ln1a = (const float*)d_in[2];
    const float* ln1b = (const float*)d_in[3];
    const float* ln2a = (const float*)d_in[4];
    const float* ln2b = (const float*)d_in[5];
    const float* wq   = (const float*)d_in[6];
    const float* wk   = (const float*)d_in[7];
    const float* wv   = (const float*)d_in[8];
    const float* wo   = (const float*)d_in[9];
    const float* w1   = (const float*)d_in[10];
    const float* b1   = (const float*)d_in[11];
    const float* w2   = (const float*)d_in[12];
    const float* b2   = (const float*)d_in[13];
    float* out = (float*)d_out;

    // Workspace: 72 MB, liveness-overlapped 16MB slots.
    char* ws = (char*)d_ws;
    const size_t MB16 = (size_t)16 * 1024 * 1024;
    u16* y1      = (u16*)(ws + 0 * MB16);
    u16* q       = (u16*)(ws + 1 * MB16);
    u16* k       = (u16*)(ws + 2 * MB16);
    u16* v       = (u16*)(ws + 3 * MB16);
    u16* wqt     = (u16*)(ws + 4 * MB16 + 0 * (size_t)D_ * D_ * 2);
    u16* wkt     = (u16*)(ws + 4 * MB16 + 1 * (size_t)D_ * D_ * 2);
    u16* wvt     = (u16*)(ws + 4 * MB16 + 2 * (size_t)D_ * D_ * 2);
    u16* wot     = (u16*)(ws + 4 * MB16 + 3 * (size_t)D_ * D_ * 2);
    u16* y2      = y1;
    u16* w1t     = q;
    u16* w2t     = q + (size_t)D_ * DFF;
    u16* h_full  = k;
    u16* ctx     = v;
    u16*   vt  = (u16*)d_out;                // d_out scratch; dead after attn
    float* x1f = out;

    dim3 tb(32, 8);
    transpose_f2b4<<<dim3(D_/32, D_/32, 4), tb, 0, stream>>>(
        wq, wk, wv, wo, wqt, wkt, wvt, wot, D_, D_);

    ln_kernel<<<NT, 256, 0, stream>>>(x, ln1a, ln1b, y1);

    // fused QKV: wqt/wkt/wvt are contiguous -> one [3072][1024] B matrix
    gemm8p<<<dim3(3*D_/BN2, NT/BM2), 512, 0, stream>>>(
        y1, wqt, q, k, v, 3*D_, D_, 0, nullptr);

    transpose_v<<<dim3(S_/32, 2, B_*H_), tb, 0, stream>>>(v, vt);

    attn_kernel<<<dim3(B_*H_, 16), 128, 0, stream>>>(q, k, vt, am, ctx);

    gemm_bt<<<dim3(D_/BN, NT/BM, 1), 256, 0, stream>>>(
        ctx, wot, wot, wot, x1f, x1f, x1f, NT, D_, D_, 1, nullptr, x);

    transpose_f2b<<<dim3(DFF/32, D_/32), tb, 0, stream>>>(w1, w1t, D_, DFF);
    transpose_f2b<<<dim3(D_/32, DFF/32), tb, 0, stream>>>(w2, w2t, DFF, D_);

    ln_kernel<<<NT, 256, 0, stream>>>(x1f, ln2a, ln2b, y2);

    gemm8p<<<dim3(DFF/BN2, NT/BM2), 512, 0, stream>>>(
        y2, w1t, h_full, h_full, h_full, DFF, D_, 2, b1);
    gemm_bt<<<dim3(D_/BN, NT/BM, 1), 256, 0, stream>>>(
        h_full, w2t, w2t, w2t, out, out, out, NT, D_, DFF, 3, b2, x1f);
}

// Round 11
// 622.195 us; speedup vs baseline: 1.3368x; 1.0127x over previous
//
#include <hip/hip_runtime.h>
#include <math.h>

typedef unsigned short u16;
typedef unsigned int u32;
typedef __attribute__((ext_vector_type(4))) unsigned short u16x4;
typedef __attribute__((ext_vector_type(8))) short bf16x8;
typedef __attribute__((ext_vector_type(4))) float f32x4;

#define B_ 4
#define S_ 2048
#define D_ 1024
#define H_ 16
#define NT (B_*S_)
#define DFF 4096

static __device__ __forceinline__ float bf2f(u16 u) {
    return __uint_as_float(((u32)u) << 16);
}
static __device__ __forceinline__ u16 f2bf(float f) {
    u32 u = __float_as_uint(f);
    u32 r = (u + 0x7fffu + ((u >> 16) & 1u)) >> 16;
    return (u16)r;
}
// async 16B/lane global->LDS (LDS dest = wave-uniform base + lane*16)
static __device__ __forceinline__ void gload_lds16(const void* g, void* l) {
    __builtin_amdgcn_global_load_lds(
        (const __attribute__((address_space(1))) void*)g,
        (__attribute__((address_space(3))) void*)l, 16, 0, 0);
}
// tanh-form GELU via hw exp2 (validated R14: passed absmax 0.0625).
static __device__ __forceinline__ float gelu_fast(float x) {
    float x2 = x * x;
    float u = x * fmaf(0.044715f, x2, 1.0f);
    float e = exp2f(2.3022079f * u);
    float r = __builtin_amdgcn_rcpf(e + 1.0f);
    return x - x * r;
}

// raw barrier (no implicit vmcnt(0) drain, unlike __syncthreads) with
// compiler memory fences so C++ LDS reads can't be hoisted across it.
#define MBAR() do { asm volatile("" ::: "memory"); \
                    __builtin_amdgcn_s_barrier(); \
                    asm volatile("" ::: "memory"); } while (0)

// ------------------------------------------------- transpose fp32 -> bf16
__global__ void transpose_f2b4(const float* __restrict__ s0, const float* __restrict__ s1,
                               const float* __restrict__ s2, const float* __restrict__ s3,
                               u16* __restrict__ d0, u16* __restrict__ d1,
                               u16* __restrict__ d2, u16* __restrict__ d3,
                               int R, int C) {
    const float* in = s0; u16* out = d0;
    if (blockIdx.z == 1) { in = s1; out = d1; }
    else if (blockIdx.z == 2) { in = s2; out = d2; }
    else if (blockIdx.z == 3) { in = s3; out = d3; }
    __shared__ float t[32][33];
    int c0 = blockIdx.x * 32, r0 = blockIdx.y * 32;
    int x = threadIdx.x, y = threadIdx.y;
    #pragma unroll
    for (int i = 0; i < 4; i++)
        t[y + i*8][x] = in[(long)(r0 + y + i*8) * C + c0 + x];
    __syncthreads();
    #pragma unroll
    for (int i = 0; i < 4; i++)
        out[(long)(c0 + y + i*8) * R + r0 + x] = f2bf(t[x][y + i*8]);
}

__global__ void transpose_f2b(const float* __restrict__ in, u16* __restrict__ out,
                              int R, int C) {
    __shared__ float t[32][33];
    int c0 = blockIdx.x * 32, r0 = blockIdx.y * 32;
    int x = threadIdx.x, y = threadIdx.y;
    #pragma unroll
    for (int i = 0; i < 4; i++)
        t[y + i*8][x] = in[(long)(r0 + y + i*8) * C + c0 + x];
    __syncthreads();
    #pragma unroll
    for (int i = 0; i < 4; i++)
        out[(long)(c0 + y + i*8) * R + r0 + x] = f2bf(t[x][y + i*8]);
}

// V bf16 [B*S][D] -> Vt bf16 [B*H][64][S]. grid (S/32, 2, B*H), block (32,8)
__global__ void transpose_v(const u16* __restrict__ V, u16* __restrict__ Vt) {
    __shared__ u16 t[32][33];
    int z = blockIdx.z; int b = z >> 4, h = z & 15;
    int s0 = blockIdx.x * 32, d0 = blockIdx.y * 32;
    int x = threadIdx.x, y = threadIdx.y;
    const u16* in = V + ((long)b * S_ + s0) * D_ + h * 64 + d0;
    #pragma unroll
    for (int i = 0; i < 4; i++)
        t[y + i*8][x] = in[(long)(y + i*8) * D_ + x];
    __syncthreads();
    u16* out = Vt + ((long)z * 64 + d0) * S_ + s0;
    #pragma unroll
    for (int i = 0; i < 4; i++)
        out[(long)(y + i*8) * S_ + x] = t[x][y + i*8];
}

// ------------------------------------------------- layernorm (fp32 in, bf16 out)
__global__ __launch_bounds__(256) void ln_kernel(
    const float* __restrict__ X, const float* __restrict__ alpha,
    const float* __restrict__ beta, u16* __restrict__ Y) {
    int row = blockIdx.x, tid = threadIdx.x;
    float4 xv = ((const float4*)(X + (long)row * D_))[tid];
    float v[4] = {xv.x, xv.y, xv.z, xv.w};
    float s = 0.f, ss = 0.f;
    #pragma unroll
    for (int i = 0; i < 4; i++) { s += v[i]; ss += v[i]*v[i]; }
    #pragma unroll
    for (int off = 32; off >= 1; off >>= 1) {
        s += __shfl_xor(s, off);
        ss += __shfl_xor(ss, off);
    }
    __shared__ float red[8];
    __shared__ float stats[2];
    int w = tid >> 6;
    if ((tid & 63) == 0) { red[w] = s; red[4 + w] = ss; }
    __syncthreads();
    if (tid == 0) {
        float S = red[0] + red[1] + red[2] + red[3];
        float SS = red[4] + red[5] + red[6] + red[7];
        float mean = S * (1.f / D_);
        float var = SS * (1.f / D_) - mean * mean;
        stats[0] = mean; stats[1] = rsqrtf(var + 1e-5f);
    }
    __syncthreads();
    float mean = stats[0], rstd = stats[1];
    float4 av = ((const float4*)alpha)[tid];
    float4 bv = ((const float4*)beta)[tid];
    u16x4 o;
    o[0] = f2bf((v[0] - mean) * rstd * av.x + bv.x);
    o[1] = f2bf((v[1] - mean) * rstd * av.y + bv.y);
    o[2] = f2bf((v[2] - mean) * rstd * av.z + bv.z);
    o[3] = f2bf((v[3] - mean) * rstd * av.w + bv.w);
    *(u16x4*)(Y + (long)row * D_ + tid * 4) = o;
}

// ------------------------------------------------- GEMM 128^2 (Wo only now)
// BASELINE m97 recipe, untouched.
#define BM 128
#define BN 128
#define BK 64

__global__ __launch_bounds__(256, 3) void gemm_bt(
    const u16* __restrict__ A,
    const u16* __restrict__ Bt0, const u16* __restrict__ Bt1, const u16* __restrict__ Bt2,
    void* __restrict__ C0, void* __restrict__ C1, void* __restrict__ C2,
    int M, int N, int K, int mode,
    const float* __restrict__ bias, const float* __restrict__ resid) {
    const u16* Bt = Bt0; void* C = C0;
    if (blockIdx.z == 1) { Bt = Bt1; C = C1; }
    else if (blockIdx.z == 2) { Bt = Bt2; C = C2; }

    __shared__ __align__(16) u16 Asm[BM * BK];
    __shared__ __align__(16) u16 Bsm[BN * BK];

    int tid = threadIdx.x;
    int lane = tid & 63, wave = tid >> 6;
    int l15 = lane & 15, quad = lane >> 4;
    int wm = wave & 1, wn = wave >> 1;
    long tm0 = (long)blockIdx.y * BM, tn0 = (long)blockIdx.x * BN;

    int srow = lane >> 3;
    int scol = (lane & 7) * 8;

    f32x4 acc[4][4] = {};

    for (int k0 = 0; k0 < K; k0 += BK) {
        __syncthreads();
        #pragma unroll
        for (int c = 0; c < 4; c++) {
            int chunk = wave * 4 + c;
            int row = chunk * 8 + srow;
            gload_lds16(&A[(tm0 + row) * (long)K + k0 + scol], &Asm[chunk * 512]);
            gload_lds16(&Bt[(tn0 + row) * (long)K + k0 + scol], &Bsm[chunk * 512]);
        }
        __syncthreads();
        #pragma unroll
        for (int ks = 0; ks < 2; ks++) {
            bf16x8 af[4], bfm[4];
            #pragma unroll
            for (int mt = 0; mt < 4; mt++)
                af[mt] = *(const bf16x8*)&Asm[(wm*64 + mt*16 + l15) * BK + ks*32 + quad*8];
            #pragma unroll
            for (int nt = 0; nt < 4; nt++)
                bfm[nt] = *(const bf16x8*)&Bsm[(wn*64 + nt*16 + l15) * BK + ks*32 + quad*8];
            #pragma unroll
            for (int mt = 0; mt < 4; mt++)
                #pragma unroll
                for (int nt = 0; nt < 4; nt++)
                    acc[mt][nt] = __builtin_amdgcn_mfma_f32_16x16x32_bf16(
                        af[mt], bfm[nt], acc[mt][nt], 0, 0, 0);
        }
    }

    #pragma unroll
    for (int mt = 0; mt < 4; mt++) {
        #pragma unroll
        for (int nt = 0; nt < 4; nt++) {
            #pragma unroll
            for (int i = 0; i < 4; i++) {
                long r = tm0 + wm*64 + mt*16 + quad*4 + i;
                long cn = tn0 + wn*64 + nt*16 + l15;
                long idx = r * N + cn;
                float val = acc[mt][nt][i];
                if (mode == 0) {
                    ((u16*)C)[idx] = f2bf(val);
                } else if (mode == 1) {
                    ((float*)C)[idx] = val + resid[idx];
                } else if (mode == 2) {
                    val += bias[cn];
                    ((u16*)C)[idx] = f2bf(gelu_fast(val));
                } else {
                    ((float*)C)[idx] = val + bias[cn] + resid[idx];
                }
            }
        }
    }
}

// ------------------------------------------------- GEMM 256^2 8-phase (QKV fused, W1)
// R16 kernel (KEEP): 8-phase counted-vmcnt schedule + T2 XOR swizzle.
// Verified: ~120 us each (W1 ~573 TF), conflicts fixed.
#define BM2 256
#define BN2 256
#define BK2 64

__global__ __launch_bounds__(512, 2) void gemm8p(
    const u16* __restrict__ A, const u16* __restrict__ Bt,
    u16* __restrict__ C0, u16* __restrict__ C1, u16* __restrict__ C2,
    int N, int K, int mode, const float* __restrict__ bias) {
    __shared__ __align__(16) u16 lds[2 * 32768];   // 128 KB

    int tid = threadIdx.x;
    int lane = tid & 63, wave = tid >> 6;          // wave 0..7
    int l15 = lane & 15, quad = lane >> 4;
    int wm = wave & 1, wn = wave >> 1;             // M half, N quarter
    long tm0 = (long)blockIdx.y * BM2, tn0 = (long)blockIdx.x * BN2;
    int srow = lane >> 3;
    int scolw = ((lane & 7) ^ srow) * 8;           // T2 write-side inverse swizzle
    int sk = l15 & 7;
    int ca0 = ((quad) ^ sk) * 8;                   // T2 read-side
    int ca1 = ((4 + quad) ^ sk) * 8;
    int steps = K >> 6;

    auto STAGE = [&](int kt, int half, int buf) {
        long kk = (long)kt * BK2;
        #pragma unroll
        for (int c = 0; c < 2; c++) {
            int chunk = wave * 2 + c;                       // 0..15
            int rloc = (half & 1) * 128 + chunk * 8 + srow; // row in tile
            const u16* g = (half < 2)
                ? &A [(tm0 + rloc) * (long)K + kk + scolw]
                : &Bt[(tn0 + rloc) * (long)K + kk + scolw];
            u16* l = &lds[buf * 32768 + (half >= 2 ? 16384 : 0)
                          + (half & 1) * 8192 + chunk * 512];
            gload_lds16(g, l);
        }
    };

    f32x4 acc[8][4] = {};
    bf16x8 af[4][2], bl[2][2], bh[2][2];

    STAGE(0, 0, 0); STAGE(0, 1, 0); STAGE(0, 2, 0); STAGE(0, 3, 0);
    if (steps > 1) { STAGE(1, 2, 1); STAGE(1, 3, 1); }
    if (steps > 1) asm volatile("s_waitcnt vmcnt(4)" ::: "memory");
    else           asm volatile("s_waitcnt vmcnt(0)" ::: "memory");
    MBAR();

    for (int t = 0; t < steps; ++t) {
        int cur = t & 1;
        const u16* Ab = &lds[cur * 32768];
        const u16* Bb = &lds[cur * 32768 + 16384];
        bool pf1 = (t + 1 < steps), pf2 = (t + 2 < steps);

        // ph1
        #pragma unroll
        for (int mt = 0; mt < 4; mt++) {
            int row = wm*128 + mt*16 + l15;
            af[mt][0] = *(const bf16x8*)&Ab[row * BK2 + ca0];
            af[mt][1] = *(const bf16x8*)&Ab[row * BK2 + ca1];
        }
        #pragma unroll
        for (int nt = 0; nt < 2; nt++) {
            int row = wn*64 + nt*16 + l15;
            bl[nt][0] = *(const bf16x8*)&Bb[row * BK2 + ca0];
            bl[nt][1] = *(const bf16x8*)&Bb[row * BK2 + ca1];
        }
        if (pf1) STAGE(t + 1, 0, cur ^ 1);
        MBAR();
        __builtin_amdgcn_s_setprio(1);
        #pragma unroll
        for (int mt = 0; mt < 4; mt++)
            #pragma unroll
            for (int nt = 0; nt < 2; nt++) {
                acc[mt][nt] = __builtin_amdgcn_mfma_f32_16x16x32_bf16(af[mt][0], bl[nt][0], acc[mt][nt], 0,0,0);
                acc[mt][nt] = __builtin_amdgcn_mfma_f32_16x16x32_bf16(af[mt][1], bl[nt][1], acc[mt][nt], 0,0,0);
            }
        __builtin_amdgcn_s_setprio(0);
        MBAR();

        // ph2
        #pragma unroll
        for (int nt = 0; nt < 2; nt++) {
            int row = wn*64 + (2+nt)*16 + l15;
            bh[nt][0] = *(const bf16x8*)&Bb[row * BK2 + ca0];
            bh[nt][1] = *(const bf16x8*)&Bb[row * BK2 + ca1];
        }
        if (pf1) STAGE(t + 1, 1, cur ^ 1);
        MBAR();
        __builtin_amdgcn_s_setprio(1);
        #pragma unroll
        for (int mt = 0; mt < 4; mt++)
            #pragma unroll
            for (int nt = 0; nt < 2; nt++) {
                acc[mt][2+nt] = __builtin_amdgcn_mfma_f32_16x16x32_bf16(af[mt][0], bh[nt][0], acc[mt][2+nt], 0,0,0);
                acc[mt][2+nt] = __builtin_amdgcn_mfma_f32_16x16x32_bf16(af[mt][1], bh[nt][1], acc[mt][2+nt], 0,0,0);
            }
        __builtin_amdgcn_s_setprio(0);
        MBAR();

        // ph3
        #pragma unroll
        for (int mt = 0; mt < 4; mt++) {
            int row = wm*128 + 64 + mt*16 + l15;
            af[mt][0] = *(const bf16x8*)&Ab[row * BK2 + ca0];
            af[mt][1] = *(const bf16x8*)&Ab[row * BK2 + ca1];
        }
        if (pf2) STAGE(t + 2, 2, cur);
        MBAR();
        __builtin_amdgcn_s_setprio(1);
        #pragma unroll
        for (int mt = 0; mt < 4; mt++)
            #pragma unroll
            for (int nt = 0; nt < 2; nt++) {
                acc[4+mt][2+nt] = __builtin_amdgcn_mfma_f32_16x16x32_bf16(af[mt][0], bh[nt][0], acc[4+mt][2+nt], 0,0,0);
                acc[4+mt][2+nt] = __builtin_amdgcn_mfma_f32_16x16x32_bf16(af[mt][1], bh[nt][1], acc[4+mt][2+nt], 0,0,0);
            }
        __builtin_amdgcn_s_setprio(0);
        MBAR();

        // ph4
        if (pf2) STAGE(t + 2, 3, cur);
        MBAR();
        __builtin_amdgcn_s_setprio(1);
        #pragma unroll
        for (int mt = 0; mt < 4; mt++)
            #pragma unroll
            for (int nt = 0; nt < 2; nt++) {
                acc[4+mt][nt] = __builtin_amdgcn_mfma_f32_16x16x32_bf16(af[mt][0], bl[nt][0], acc[4+mt][nt], 0,0,0);
                acc[4+mt][nt] = __builtin_amdgcn_mfma_f32_16x16x32_bf16(af[mt][1], bl[nt][1], acc[4+mt][nt], 0,0,0);
            }
        __builtin_amdgcn_s_setprio(0);
        if (pf2) asm volatile("s_waitcnt vmcnt(4)" ::: "memory");
        else     asm volatile("s_waitcnt vmcnt(0)" ::: "memory");
        MBAR();
    }

    #pragma unroll
    for (int mt = 0; mt < 8; mt++) {
        #pragma unroll
        for (int nt = 0; nt < 4; nt++) {
            #pragma unroll
            for (int i = 0; i < 4; i++) {
                long r = tm0 + wm*128 + mt*16 + quad*4 + i;
                int cn = (int)tn0 + wn*64 + nt*16 + l15;
                float val = acc[mt][nt][i];
                if (mode == 0) {           // fused QKV: route to q/k/v slabs
                    int mi = cn >> 10;
                    int col = cn & 1023;
                    u16* base = (mi == 0) ? C0 : (mi == 1 ? C1 : C2);
                    base[r * 1024 + col] = f2bf(val);
                } else {                   // mode 2: bias + GELU -> bf16
                    val += bias[cn];
                    C0[r * (long)N + cn] = f2bf(gelu_fast(val));
                }
            }
        }
    }
}

// ------------------------------------------------- GEMM 256x128 8-phase (W2)
// R19: W2 (M=8192, N=1024, K=4096) was ~140-150 us at 458 TF on the
// 2-phase gemm_bt. This variant keeps the R16 8-phase counted-vmcnt +
// T2-swizzle schedule but with a 256x128 tile -> grid (8,32) = 256 blocks
// = exactly 1 block/CU (full chip). K=4096 = 64 K-tiles amortizes the
// pipeline far deeper than W1's 16. Per-wave output 128x32 (acc[8][2]);
// quadrants (mlo/mhi)x(c0/c1), 8 MFMA each; bl held ph1->ph4. Staging per
// K-tile: ph1 A-lo(t+1) 2ld, ph2 A-hi(t+1) 2ld, ph3 B-lo(t+2) 1ld,
// ph4 B-hi(t+2) 1ld; tile-end vmcnt(2) leaves B(t+2) in flight.
// LDS 96 KB = 2 bufs x (A 32KB + B 16KB). Output: f32 + bias + resid.
__global__ __launch_bounds__(512, 2) void gemm8p_n128(
    const u16* __restrict__ A, const u16* __restrict__ Bt,
    float* __restrict__ C, int N, int K,
    const float* __restrict__ bias, const float* __restrict__ resid) {
    __shared__ __align__(16) u16 lds[2 * 24576];   // 96 KB

    int tid = threadIdx.x;
    int lane = tid & 63, wave = tid >> 6;          // 0..7
    int l15 = lane & 15, quad = lane >> 4;
    int wm = wave & 1, wn = wave >> 1;             // M half(128 rows), N quarter(32 cols)
    long tm0 = (long)blockIdx.y * 256, tn0 = (long)blockIdx.x * 128;
    int srow = lane >> 3;
    int scolw = ((lane & 7) ^ srow) * 8;           // T2 write-side
    int sk = l15 & 7;
    int ca0 = ((quad) ^ sk) * 8;                   // T2 read-side
    int ca1 = ((4 + quad) ^ sk) * 8;
    int steps = K >> 6;

    // half: 0=A rows 0-127 (2 ld/thr), 1=A rows 128-255 (2), 2=B rows 0-63 (1), 3=B rows 64-127 (1)
    auto STAGE = [&](int kt, int half, int buf) {
        long kk = (long)kt * 64;
        if (half < 2) {
            #pragma unroll
            for (int c = 0; c < 2; c++) {
                int chunk = wave * 2 + c;                    // 0..15
                int rloc = half * 128 + chunk * 8 + srow;
                gload_lds16(&A[(tm0 + rloc) * (long)K + kk + scolw],
                            &lds[buf * 24576 + half * 8192 + chunk * 512]);
            }
        } else {
            int rloc = (half - 2) * 64 + wave * 8 + srow;
            gload_lds16(&Bt[(tn0 + rloc) * (long)K + kk + scolw],
                        &lds[buf * 24576 + 16384 + (half - 2) * 4096 + wave * 512]);
        }
    };

    f32x4 acc[8][2] = {};
    bf16x8 af[4][2], bl[2], bh[2];

    STAGE(0, 0, 0); STAGE(0, 1, 0); STAGE(0, 2, 0); STAGE(0, 3, 0);   // 6 loads
    if (steps > 1) { STAGE(1, 2, 1); STAGE(1, 3, 1); }                 // 2 loads
    if (steps > 1) asm volatile("s_waitcnt vmcnt(2)" ::: "memory");
    else           asm volatile("s_waitcnt vmcnt(0)" ::: "memory");
    MBAR();

    for (int t = 0; t < steps; ++t) {
        int cur = t & 1;
        const u16* Ab = &lds[cur * 24576];
        const u16* Bb = &lds[cur * 24576 + 16384];
        bool pf1 = (t + 1 < steps), pf2 = (t + 2 < steps);

        // ph1: read af-mlo + bl; stage A-lo(t+1); MFMA acc[0:4][0]
        #pragma unroll
        for (int mt = 0; mt < 4; mt++) {
            int row = wm*128 + mt*16 + l15;
            af[mt][0] = *(const bf16x8*)&Ab[row * 64 + ca0];
            af[mt][1] = *(const bf16x8*)&Ab[row * 64 + ca1];
        }
        {
            int row = wn*32 + l15;
            bl[0] = *(const bf16x8*)&Bb[row * 64 + ca0];
            bl[1] = *(const bf16x8*)&Bb[row * 64 + ca1];
        }
        if (pf1) STAGE(t + 1, 0, cur ^ 1);
        MBAR();
        __builtin_amdgcn_s_setprio(1);
        #pragma unroll
        for (int mt = 0; mt < 4; mt++) {
            acc[mt][0] = __builtin_amdgcn_mfma_f32_16x16x32_bf16(af[mt][0], bl[0], acc[mt][0], 0,0,0);
            acc[mt][0] = __builtin_amdgcn_mfma_f32_16x16x32_bf16(af[mt][1], bl[1], acc[mt][0], 0,0,0);
        }
        __builtin_amdgcn_s_setprio(0);
        MBAR();

        // ph2: read bh; stage A-hi(t+1); MFMA acc[0:4][1]
        {
            int row = wn*32 + 16 + l15;
            bh[0] = *(const bf16x8*)&Bb[row * 64 + ca0];
            bh[1] = *(const bf16x8*)&Bb[row * 64 + ca1];
        }
        if (pf1) STAGE(t + 1, 1, cur ^ 1);
        MBAR();
        __builtin_amdgcn_s_setprio(1);
        #pragma unroll
        for (int mt = 0; mt < 4; mt++) {
            acc[mt][1] = __builtin_amdgcn_mfma_f32_16x16x32_bf16(af[mt][0], bh[0], acc[mt][1], 0,0,0);
            acc[mt][1] = __builtin_amdgcn_mfma_f32_16x16x32_bf16(af[mt][1], bh[1], acc[mt][1], 0,0,0);
        }
        __builtin_amdgcn_s_setprio(0);
        MBAR();

        // ph3: read af-mhi; stage B-lo(t+2); MFMA acc[4:8][1]
        #pragma unroll
        for (int mt = 0; mt < 4; mt++) {
            int row = wm*128 + 64 + mt*16 + l15;
            af[mt][0] = *(const bf16x8*)&Ab[row * 64 + ca0];
            af[mt][1] = *(const bf16x8*)&Ab[row * 64 + ca1];
        }
        if (pf2) STAGE(t + 2, 2, cur);
        MBAR();
        __builtin_amdgcn_s_setprio(1);
        #pragma unroll
        for (int mt = 0; mt < 4; mt++) {
            acc[4+mt][1] = __builtin_amdgcn_mfma_f32_16x16x32_bf16(af[mt][0], bh[0], acc[4+mt][1], 0,0,0);
            acc[4+mt][1] = __builtin_amdgcn_mfma_f32_16x16x32_bf16(af[mt][1], bh[1], acc[4+mt][1], 0,0,0);
        }
        __builtin_amdgcn_s_setprio(0);
        MBAR();

        // ph4: stage B-hi(t+2); MFMA acc[4:8][0] (bl held); tile-end counted vmcnt
        if (pf2) STAGE(t + 2, 3, cur);
        MBAR();
        __builtin_amdgcn_s_setprio(1);
        #pragma unroll
        for (int mt = 0; mt < 4; mt++) {
            acc[4+mt][0] = __builtin_amdgcn_mfma_f32_16x16x32_bf16(af[mt][0], bl[0], acc[4+mt][0], 0,0,0);
            acc[4+mt][0] = __builtin_amdgcn_mfma_f32_16x16x32_bf16(af[mt][1], bl[1], acc[4+mt][0], 0,0,0);
        }
        __builtin_amdgcn_s_setprio(0);
        if (pf2) asm volatile("s_waitcnt vmcnt(2)" ::: "memory");
        else     asm volatile("s_waitcnt vmcnt(0)" ::: "memory");
        MBAR();
    }

    #pragma unroll
    for (int mt = 0; mt < 8; mt++) {
        #pragma unroll
        for (int nt = 0; nt < 2; nt++) {
            #pragma unroll
            for (int i = 0; i < 4; i++) {
                long r = tm0 + wm*128 + mt*16 + quad*4 + i;
                int cn = (int)tn0 + wn*32 + nt*16 + l15;
                long idx = r * (long)N + cn;
                C[idx] = acc[mt][nt][i] + bias[cn] + resid[idx];
            }
        }
    }
}

// ------------------------------------------------- attention
// R19: SOFTWARE-PIPELINED chain (T15 analog). Occupancy moves (R12/R13/
// R18) all null: residency pins at ~6 waves/CU, issue utilization ~17% —
// the per-iteration serial chain {loads -> QK -> softmax -> 32 ds_writes
// -> lgkmcnt(0) -> P reads -> PV} is the wall. Fix: QK hoisted one
// iteration ahead. Per iter: vb(t)+kb(t+1) loads issue first; softmax(t)
// (~500cyc VALU) hides kb latency; QK(t+1)->s_next issues while the
// ds_writes drain (fence then ~free); PV(t) uses vb loaded ~700cyc ago.
// All global latency + fence off the critical path. +32 VGPR (s_next);
// kbn double-buffer dropped (kb regs free after hoisted QK).
#define LDP 72   // P row stride in u16

__global__ __launch_bounds__(128, 2) void attn_kernel(
    const u16* __restrict__ Q, const u16* __restrict__ Kg, const u16* __restrict__ Vt,
    const int* __restrict__ mask, u16* __restrict__ O) {
    __shared__ __align__(16) u16 Psm[2][32 * LDP];   // 9.2 KB
    int tid = threadIdx.x;
    int lane = tid & 63, wave = tid >> 6;            // 0..1
    int l15 = lane & 15, quad = lane >> 4;
    int bh = blockIdx.x; int b = bh >> 4, h = bh & 15;
    int j = blockIdx.y * 2 + wave;     // pair index 0..31
    long tokBase = (long)b * S_;
    const float SCL = 0.125f * 1.4426950408889634f;  // exp2 domain
    const float MMAX = 20.0f;                        // fixed softmax shift

    const bf16x8 ones = {16256,16256,16256,16256,16256,16256,16256,16256}; // bf16 1.0
    u16* Pw = Psm[wave];
    const int* mb = mask + b * S_;

    #pragma unroll
    for (int half = 0; half < 2; half++) {
        int t = half ? (63 - j) : j;   // q-tile index 0..63 (balanced pair)
        int q0 = t * 32;

        bf16x8 aq[2][2];
        #pragma unroll
        for (int mt = 0; mt < 2; mt++) {
            const u16* qptr = Q + (tokBase + q0 + mt*16 + l15) * D_ + h * 64;
            aq[mt][0] = *(const bf16x8*)(qptr + quad * 8);
            aq[mt][1] = *(const bf16x8*)(qptr + 32 + quad * 8);
        }

        f32x4 o[2][4] = {};
        f32x4 lacc[2] = {};
        int ktiles = t / 2 + 1;

        // prologue: load K(0), compute QK(0) -> s
        bf16x8 kb[4][2];
        #pragma unroll
        for (int nt = 0; nt < 4; nt++) {
            const u16* kp = Kg + (tokBase + nt*16 + l15) * D_ + h * 64;
            kb[nt][0] = *(const bf16x8*)(kp + quad * 8);
            kb[nt][1] = *(const bf16x8*)(kp + 32 + quad * 8);
        }
        f32x4 s[2][4] = {};
        #pragma unroll
        for (int nt = 0; nt < 4; nt++) {
            s[0][nt] = __builtin_amdgcn_mfma_f32_16x16x32_bf16(aq[0][0], kb[nt][0], s[0][nt], 0,0,0);
            s[0][nt] = __builtin_amdgcn_mfma_f32_16x16x32_bf16(aq[0][1], kb[nt][1], s[0][nt], 0,0,0);
            s[1][nt] = __builtin_amdgcn_mfma_f32_16x16x32_bf16(aq[1][0], kb[nt][0], s[1][nt], 0,0,0);
            s[1][nt] = __builtin_amdgcn_mfma_f32_16x16x32_bf16(aq[1][1], kb[nt][1], s[1][nt], 0,0,0);
        }

        for (int kt = 0; kt < ktiles; kt++) {
            int k0 = kt * 64;
            // V(t) loads — consumed ~700cyc later in PV
            bf16x8 vb[4][2];
            #pragma unroll
            for (int d = 0; d < 4; d++) {
                const u16* vp = Vt + ((long)bh * 64 + d*16 + l15) * S_ + k0;
                vb[d][0] = *(const bf16x8*)(vp + quad * 8);
                vb[d][1] = *(const bf16x8*)(vp + 32 + quad * 8);
            }
            // K(t+1) loads — consumed by QK(t+1) after softmax (clamped on last)
            int k1 = (kt + 1 < ktiles) ? k0 + 64 : k0;
            #pragma unroll
            for (int nt = 0; nt < 4; nt++) {
                const u16* kp = Kg + (tokBase + k1 + nt*16 + l15) * D_ + h * 64;
                kb[nt][0] = *(const bf16x8*)(kp + quad * 8);
                kb[nt][1] = *(const bf16x8*)(kp + 32 + quad * 8);
            }

            int mk = 0;
            #pragma unroll
            for (int nt = 0; nt < 4; nt++)
                if (mb[k0 + nt*16 + l15] != 0) mk |= (1 << nt);

            // softmax on s (scores for tile kt) + P writes
            #pragma unroll
            for (int mt = 0; mt < 2; mt++) {
                #pragma unroll
                for (int i = 0; i < 4; i++) {
                    int qq = q0 + mt*16 + quad*4 + i;
                    #pragma unroll
                    for (int nt = 0; nt < 4; nt++) {
                        int kc = k0 + nt*16 + l15;
                        float p = exp2f(fmaf(s[mt][nt][i], SCL, -MMAX));
                        p = (kc <= qq && ((mk >> nt) & 1)) ? p : 0.f;
                        Pw[(mt*16 + quad*4 + i) * LDP + nt*16 + l15] = f2bf(p);
                    }
                }
            }

            // QK(t+1) -> s_next: MFMA issues while the P ds_writes drain,
            // so the lgkmcnt fence below is ~free. kb latency was hidden
            // under the softmax VALU above.
            f32x4 sn[2][4] = {};
            if (kt + 1 < ktiles) {
                #pragma unroll
                for (int nt = 0; nt < 4; nt++) {
                    sn[0][nt] = __builtin_amdgcn_mfma_f32_16x16x32_bf16(aq[0][0], kb[nt][0], sn[0][nt], 0,0,0);
                    sn[0][nt] = __builtin_amdgcn_mfma_f32_16x16x32_bf16(aq[0][1], kb[nt][1], sn[0][nt], 0,0,0);
                    sn[1][nt] = __builtin_amdgcn_mfma_f32_16x16x32_bf16(aq[1][0], kb[nt][0], sn[1][nt], 0,0,0);
                    sn[1][nt] = __builtin_amdgcn_mfma_f32_16x16x32_bf16(aq[1][1], kb[nt][1], sn[1][nt], 0,0,0);
                }
            }

            // same-wave P write -> read ordering (LDS only)
            asm volatile("s_waitcnt lgkmcnt(0)" ::: "memory");

            #pragma unroll
            for (int hv = 0; hv < 2; hv++) {
                bf16x8 ap0 = *(const bf16x8*)&Pw[l15 * LDP + hv*32 + quad*8];
                bf16x8 ap1 = *(const bf16x8*)&Pw[(16 + l15) * LDP + hv*32 + quad*8];
                #pragma unroll
                for (int d = 0; d < 4; d++) {
                    o[0][d] = __builtin_amdgcn_mfma_f32_16x16x32_bf16(ap0, vb[d][hv], o[0][d], 0,0,0);
                    o[1][d] = __builtin_amdgcn_mfma_f32_16x16x32_bf16(ap1, vb[d][hv], o[1][d], 0,0,0);
                }
                lacc[0] = __builtin_amdgcn_mfma_f32_16x16x32_bf16(ap0, ones, lacc[0], 0,0,0);
                lacc[1] = __builtin_amdgcn_mfma_f32_16x16x32_bf16(ap1, ones, lacc[1], 0,0,0);
            }

            // rotate scores
            #pragma unroll
            for (int mt = 0; mt < 2; mt++)
                #pragma unroll
                for (int nt = 0; nt < 4; nt++)
                    s[mt][nt] = sn[mt][nt];
        }

        #pragma unroll
        for (int mt = 0; mt < 2; mt++) {
            #pragma unroll
            for (int i = 0; i < 4; i++) {
                float inv = 1.f / lacc[mt][i];
                long r = tokBase + q0 + mt*16 + quad*4 + i;
                #pragma unroll
                for (int d = 0; d < 4; d++)
                    O[r * D_ + h*64 + d*16 + l15] = f2bf(o[mt][d][i] * inv);
            }
        }
    }
}

// ------------------------------------------------- launch
extern "C" void kernel_launch(void* const* d_in, const int* in_sizes, int n_in,
                              void* d_out, int out_size, void* d_ws, size_t ws_size,
                              hipStream_t stream) {
    const float* x    = (const float*)d_in[0];
    const int*   am   = (const int*)d_in[1];
    const float* ln1a = (const float*)d_in[2];
    const float* ln1b = (const float*)d_in[3];
    const float* ln2a = (const float*)d_in[4];
    const float* ln2b = (const float*)d_in[5];
    const float* wq   = (const float*)d_in[6];
    const float* wk   = (const float*)d_in[7];
    const float* wv   = (const float*)d_in[8];
    const float* wo   = (const float*)d_in[9];
    const float* w1   = (const float*)d_in[10];
    const float* b1   = (const float*)d_in[11];
    const float* w2   = (const float*)d_in[12];
    const float* b2   = (const float*)d_in[13];
    float* out = (float*)d_out;

    // Workspace: 72 MB, liveness-overlapped 16MB slots.
    char* ws = (char*)d_ws;
    const size_t MB16 = (size_t)16 * 1024 * 1024;
    u16* y1      = (u16*)(ws + 0 * MB16);
    u16* q       = (u16*)(ws + 1 * MB16);
    u16* k       = (u16*)(ws + 2 * MB16);
    u16* v       = (u16*)(ws + 3 * MB16);
    u16* wqt     = (u16*)(ws + 4 * MB16 + 0 * (size_t)D_ * D_ * 2);
    u16* wkt     = (u16*)(ws + 4 * MB16 + 1 * (size_t)D_ * D_ * 2);
    u16* wvt     = (u16*)(ws + 4 * MB16 + 2 * (size_t)D_ * D_ * 2);
    u16* wot     = (u16*)(ws + 4 * MB16 + 3 * (size_t)D_ * D_ * 2);
    u16* y2      = y1;
    u16* w1t     = q;
    u16* w2t     = q + (size_t)D_ * DFF;
    u16* h_full  = k;
    u16* ctx     = v;
    u16*   vt  = (u16*)d_out;                // d_out scratch; dead after attn
    float* x1f = out;

    dim3 tb(32, 8);
    transpose_f2b4<<<dim3(D_/32, D_/32, 4), tb, 0, stream>>>(
        wq, wk, wv, wo, wqt, wkt, wvt, wot, D_, D_);

    ln_kernel<<<NT, 256, 0, stream>>>(x, ln1a, ln1b, y1);

    // fused QKV: wqt/wkt/wvt are contiguous -> one [3072][1024] B matrix
    gemm8p<<<dim3(3*D_/BN2, NT/BM2), 512, 0, stream>>>(
        y1, wqt, q, k, v, 3*D_, D_, 0, nullptr);

    transpose_v<<<dim3(S_/32, 2, B_*H_), tb, 0, stream>>>(v, vt);

    attn_kernel<<<dim3(B_*H_, 16), 128, 0, stream>>>(q, k, vt, am, ctx);

    gemm_bt<<<dim3(D_/BN, NT/BM, 1), 256, 0, stream>>>(
        ctx, wot, wot, wot, x1f, x1f, x1f, NT, D_, D_, 1, nullptr, x);

    transpose_f2b<<<dim3(DFF/32, D_/32), tb, 0, stream>>>(w1, w1t, D_, DFF);
    transpose_f2b<<<dim3(D_/32, DFF/32), tb, 0, stream>>>(w2, w2t, DFF, D_);

    ln_kernel<<<NT, 256, 0, stream>>>(x1f, ln2a, ln2b, y2);

    gemm8p<<<dim3(DFF/BN2, NT/BM2), 512, 0, stream>>>(
        y2, w1t, h_full, h_full, h_full, DFF, D_, 2, b1);

    // W2 on the 8-phase 256x128 kernel: grid (1024/128, 8192/256) = 256 blocks
    gemm8p_n128<<<dim3(D_/128, NT/256), 512, 0, stream>>>(
        h_full, w2t, out, D_, DFF, b2, x1f);
}

// Round 12
// 605.806 us; speedup vs baseline: 1.3729x; 1.0271x over previous
//
#include <hip/hip_runtime.h>
#include <math.h>

typedef unsigned short u16;
typedef unsigned int u32;
typedef __attribute__((ext_vector_type(4))) unsigned short u16x4;
typedef __attribute__((ext_vector_type(8))) short bf16x8;
typedef __attribute__((ext_vector_type(4))) float f32x4;

#define B_ 4
#define S_ 2048
#define D_ 1024
#define H_ 16
#define NT (B_*S_)
#define DFF 4096

static __device__ __forceinline__ float bf2f(u16 u) {
    return __uint_as_float(((u32)u) << 16);
}
static __device__ __forceinline__ u16 f2bf(float f) {
    u32 u = __float_as_uint(f);
    u32 r = (u + 0x7fffu + ((u >> 16) & 1u)) >> 16;
    return (u16)r;
}
// async 16B/lane global->LDS (LDS dest = wave-uniform base + lane*16)
static __device__ __forceinline__ void gload_lds16(const void* g, void* l) {
    __builtin_amdgcn_global_load_lds(
        (const __attribute__((address_space(1))) void*)g,
        (__attribute__((address_space(3))) void*)l, 16, 0, 0);
}
// tanh-form GELU via hw exp2 (validated R14: passed absmax 0.0625).
static __device__ __forceinline__ float gelu_fast(float x) {
    float x2 = x * x;
    float u = x * fmaf(0.044715f, x2, 1.0f);
    float e = exp2f(2.3022079f * u);
    float r = __builtin_amdgcn_rcpf(e + 1.0f);
    return x - x * r;
}

// raw barrier (no implicit vmcnt(0) drain, unlike __syncthreads) with
// compiler memory fences so C++ LDS reads can't be hoisted across it.
#define MBAR() do { asm volatile("" ::: "memory"); \
                    __builtin_amdgcn_s_barrier(); \
                    asm volatile("" ::: "memory"); } while (0)

// ------------------------------------------------- transpose fp32 -> bf16
__global__ void transpose_f2b4(const float* __restrict__ s0, const float* __restrict__ s1,
                               const float* __restrict__ s2, const float* __restrict__ s3,
                               u16* __restrict__ d0, u16* __restrict__ d1,
                               u16* __restrict__ d2, u16* __restrict__ d3,
                               int R, int C) {
    const float* in = s0; u16* out = d0;
    if (blockIdx.z == 1) { in = s1; out = d1; }
    else if (blockIdx.z == 2) { in = s2; out = d2; }
    else if (blockIdx.z == 3) { in = s3; out = d3; }
    __shared__ float t[32][33];
    int c0 = blockIdx.x * 32, r0 = blockIdx.y * 32;
    int x = threadIdx.x, y = threadIdx.y;
    #pragma unroll
    for (int i = 0; i < 4; i++)
        t[y + i*8][x] = in[(long)(r0 + y + i*8) * C + c0 + x];
    __syncthreads();
    #pragma unroll
    for (int i = 0; i < 4; i++)
        out[(long)(c0 + y + i*8) * R + r0 + x] = f2bf(t[x][y + i*8]);
}

__global__ void transpose_f2b(const float* __restrict__ in, u16* __restrict__ out,
                              int R, int C) {
    __shared__ float t[32][33];
    int c0 = blockIdx.x * 32, r0 = blockIdx.y * 32;
    int x = threadIdx.x, y = threadIdx.y;
    #pragma unroll
    for (int i = 0; i < 4; i++)
        t[y + i*8][x] = in[(long)(r0 + y + i*8) * C + c0 + x];
    __syncthreads();
    #pragma unroll
    for (int i = 0; i < 4; i++)
        out[(long)(c0 + y + i*8) * R + r0 + x] = f2bf(t[x][y + i*8]);
}

// V bf16 [B*S][D] -> Vt bf16 [B*H][64][S]. grid (S/32, 2, B*H), block (32,8)
__global__ void transpose_v(const u16* __restrict__ V, u16* __restrict__ Vt) {
    __shared__ u16 t[32][33];
    int z = blockIdx.z; int b = z >> 4, h = z & 15;
    int s0 = blockIdx.x * 32, d0 = blockIdx.y * 32;
    int x = threadIdx.x, y = threadIdx.y;
    const u16* in = V + ((long)b * S_ + s0) * D_ + h * 64 + d0;
    #pragma unroll
    for (int i = 0; i < 4; i++)
        t[y + i*8][x] = in[(long)(y + i*8) * D_ + x];
    __syncthreads();
    u16* out = Vt + ((long)z * 64 + d0) * S_ + s0;
    #pragma unroll
    for (int i = 0; i < 4; i++)
        out[(long)(y + i*8) * S_ + x] = t[x][y + i*8];
}

// ------------------------------------------------- layernorm (fp32 in, bf16 out)
__global__ __launch_bounds__(256) void ln_kernel(
    const float* __restrict__ X, const float* __restrict__ alpha,
    const float* __restrict__ beta, u16* __restrict__ Y) {
    int row = blockIdx.x, tid = threadIdx.x;
    float4 xv = ((const float4*)(X + (long)row * D_))[tid];
    float v[4] = {xv.x, xv.y, xv.z, xv.w};
    float s = 0.f, ss = 0.f;
    #pragma unroll
    for (int i = 0; i < 4; i++) { s += v[i]; ss += v[i]*v[i]; }
    #pragma unroll
    for (int off = 32; off >= 1; off >>= 1) {
        s += __shfl_xor(s, off);
        ss += __shfl_xor(ss, off);
    }
    __shared__ float red[8];
    __shared__ float stats[2];
    int w = tid >> 6;
    if ((tid & 63) == 0) { red[w] = s; red[4 + w] = ss; }
    __syncthreads();
    if (tid == 0) {
        float S = red[0] + red[1] + red[2] + red[3];
        float SS = red[4] + red[5] + red[6] + red[7];
        float mean = S * (1.f / D_);
        float var = SS * (1.f / D_) - mean * mean;
        stats[0] = mean; stats[1] = rsqrtf(var + 1e-5f);
    }
    __syncthreads();
    float mean = stats[0], rstd = stats[1];
    float4 av = ((const float4*)alpha)[tid];
    float4 bv = ((const float4*)beta)[tid];
    u16x4 o;
    o[0] = f2bf((v[0] - mean) * rstd * av.x + bv.x);
    o[1] = f2bf((v[1] - mean) * rstd * av.y + bv.y);
    o[2] = f2bf((v[2] - mean) * rstd * av.z + bv.z);
    o[3] = f2bf((v[3] - mean) * rstd * av.w + bv.w);
    *(u16x4*)(Y + (long)row * D_ + tid * 4) = o;
}

// ------------------------------------------------- GEMM 256^2 8-phase (QKV fused, W1)
// R16 kernel (KEEP): 8-phase counted-vmcnt schedule + T2 XOR swizzle.
// Verified: ~120 us each (W1 ~573 TF), conflicts fixed.
#define BM2 256
#define BN2 256
#define BK2 64

__global__ __launch_bounds__(512, 2) void gemm8p(
    const u16* __restrict__ A, const u16* __restrict__ Bt,
    u16* __restrict__ C0, u16* __restrict__ C1, u16* __restrict__ C2,
    int N, int K, int mode, const float* __restrict__ bias) {
    __shared__ __align__(16) u16 lds[2 * 32768];   // 128 KB

    int tid = threadIdx.x;
    int lane = tid & 63, wave = tid >> 6;          // wave 0..7
    int l15 = lane & 15, quad = lane >> 4;
    int wm = wave & 1, wn = wave >> 1;             // M half, N quarter
    long tm0 = (long)blockIdx.y * BM2, tn0 = (long)blockIdx.x * BN2;
    int srow = lane >> 3;
    int scolw = ((lane & 7) ^ srow) * 8;           // T2 write-side inverse swizzle
    int sk = l15 & 7;
    int ca0 = ((quad) ^ sk) * 8;                   // T2 read-side
    int ca1 = ((4 + quad) ^ sk) * 8;
    int steps = K >> 6;

    auto STAGE = [&](int kt, int half, int buf) {
        long kk = (long)kt * BK2;
        #pragma unroll
        for (int c = 0; c < 2; c++) {
            int chunk = wave * 2 + c;                       // 0..15
            int rloc = (half & 1) * 128 + chunk * 8 + srow; // row in tile
            const u16* g = (half < 2)
                ? &A [(tm0 + rloc) * (long)K + kk + scolw]
                : &Bt[(tn0 + rloc) * (long)K + kk + scolw];
            u16* l = &lds[buf * 32768 + (half >= 2 ? 16384 : 0)
                          + (half & 1) * 8192 + chunk * 512];
            gload_lds16(g, l);
        }
    };

    f32x4 acc[8][4] = {};
    bf16x8 af[4][2], bl[2][2], bh[2][2];

    STAGE(0, 0, 0); STAGE(0, 1, 0); STAGE(0, 2, 0); STAGE(0, 3, 0);
    if (steps > 1) { STAGE(1, 2, 1); STAGE(1, 3, 1); }
    if (steps > 1) asm volatile("s_waitcnt vmcnt(4)" ::: "memory");
    else           asm volatile("s_waitcnt vmcnt(0)" ::: "memory");
    MBAR();

    for (int t = 0; t < steps; ++t) {
        int cur = t & 1;
        const u16* Ab = &lds[cur * 32768];
        const u16* Bb = &lds[cur * 32768 + 16384];
        bool pf1 = (t + 1 < steps), pf2 = (t + 2 < steps);

        // ph1
        #pragma unroll
        for (int mt = 0; mt < 4; mt++) {
            int row = wm*128 + mt*16 + l15;
            af[mt][0] = *(const bf16x8*)&Ab[row * BK2 + ca0];
            af[mt][1] = *(const bf16x8*)&Ab[row * BK2 + ca1];
        }
        #pragma unroll
        for (int nt = 0; nt < 2; nt++) {
            int row = wn*64 + nt*16 + l15;
            bl[nt][0] = *(const bf16x8*)&Bb[row * BK2 + ca0];
            bl[nt][1] = *(const bf16x8*)&Bb[row * BK2 + ca1];
        }
        if (pf1) STAGE(t + 1, 0, cur ^ 1);
        MBAR();
        __builtin_amdgcn_s_setprio(1);
        #pragma unroll
        for (int mt = 0; mt < 4; mt++)
            #pragma unroll
            for (int nt = 0; nt < 2; nt++) {
                acc[mt][nt] = __builtin_amdgcn_mfma_f32_16x16x32_bf16(af[mt][0], bl[nt][0], acc[mt][nt], 0,0,0);
                acc[mt][nt] = __builtin_amdgcn_mfma_f32_16x16x32_bf16(af[mt][1], bl[nt][1], acc[mt][nt], 0,0,0);
            }
        __builtin_amdgcn_s_setprio(0);
        MBAR();

        // ph2
        #pragma unroll
        for (int nt = 0; nt < 2; nt++) {
            int row = wn*64 + (2+nt)*16 + l15;
            bh[nt][0] = *(const bf16x8*)&Bb[row * BK2 + ca0];
            bh[nt][1] = *(const bf16x8*)&Bb[row * BK2 + ca1];
        }
        if (pf1) STAGE(t + 1, 1, cur ^ 1);
        MBAR();
        __builtin_amdgcn_s_setprio(1);
        #pragma unroll
        for (int mt = 0; mt < 4; mt++)
            #pragma unroll
            for (int nt = 0; nt < 2; nt++) {
                acc[mt][2+nt] = __builtin_amdgcn_mfma_f32_16x16x32_bf16(af[mt][0], bh[nt][0], acc[mt][2+nt], 0,0,0);
                acc[mt][2+nt] = __builtin_amdgcn_mfma_f32_16x16x32_bf16(af[mt][1], bh[nt][1], acc[mt][2+nt], 0,0,0);
            }
        __builtin_amdgcn_s_setprio(0);
        MBAR();

        // ph3
        #pragma unroll
        for (int mt = 0; mt < 4; mt++) {
            int row = wm*128 + 64 + mt*16 + l15;
            af[mt][0] = *(const bf16x8*)&Ab[row * BK2 + ca0];
            af[mt][1] = *(const bf16x8*)&Ab[row * BK2 + ca1];
        }
        if (pf2) STAGE(t + 2, 2, cur);
        MBAR();
        __builtin_amdgcn_s_setprio(1);
        #pragma unroll
        for (int mt = 0; mt < 4; mt++)
            #pragma unroll
            for (int nt = 0; nt < 2; nt++) {
                acc[4+mt][2+nt] = __builtin_amdgcn_mfma_f32_16x16x32_bf16(af[mt][0], bh[nt][0], acc[4+mt][2+nt], 0,0,0);
                acc[4+mt][2+nt] = __builtin_amdgcn_mfma_f32_16x16x32_bf16(af[mt][1], bh[nt][1], acc[4+mt][2+nt], 0,0,0);
            }
        __builtin_amdgcn_s_setprio(0);
        MBAR();

        // ph4
        if (pf2) STAGE(t + 2, 3, cur);
        MBAR();
        __builtin_amdgcn_s_setprio(1);
        #pragma unroll
        for (int mt = 0; mt < 4; mt++)
            #pragma unroll
            for (int nt = 0; nt < 2; nt++) {
                acc[4+mt][nt] = __builtin_amdgcn_mfma_f32_16x16x32_bf16(af[mt][0], bl[nt][0], acc[4+mt][nt], 0,0,0);
                acc[4+mt][nt] = __builtin_amdgcn_mfma_f32_16x16x32_bf16(af[mt][1], bl[nt][1], acc[4+mt][nt], 0,0,0);
            }
        __builtin_amdgcn_s_setprio(0);
        if (pf2) asm volatile("s_waitcnt vmcnt(4)" ::: "memory");
        else     asm volatile("s_waitcnt vmcnt(0)" ::: "memory");
        MBAR();
    }

    #pragma unroll
    for (int mt = 0; mt < 8; mt++) {
        #pragma unroll
        for (int nt = 0; nt < 4; nt++) {
            #pragma unroll
            for (int i = 0; i < 4; i++) {
                long r = tm0 + wm*128 + mt*16 + quad*4 + i;
                int cn = (int)tn0 + wn*64 + nt*16 + l15;
                float val = acc[mt][nt][i];
                if (mode == 0) {           // fused QKV: route to q/k/v slabs
                    int mi = cn >> 10;
                    int col = cn & 1023;
                    u16* base = (mi == 0) ? C0 : (mi == 1 ? C1 : C2);
                    base[r * 1024 + col] = f2bf(val);
                } else {                   // mode 2: bias + GELU -> bf16
                    val += bias[cn];
                    C0[r * (long)N + cn] = f2bf(gelu_fast(val));
                }
            }
        }
    }
}

// ------------------------------------------------- GEMM 256x128 8-phase (Wo, W2)
// R19 kernel (KEEP, verified): 8-phase counted-vmcnt + T2 swizzle,
// 256x128 tile -> grid 256 blocks = 1/CU. W2 ~127 us (was ~148).
// R20: also used for Wo (same N=1024 shape class, K=1024 = 16 K-tiles);
// bias==nullptr -> residual-only epilogue (Wo has no bias).
__global__ __launch_bounds__(512, 2) void gemm8p_n128(
    const u16* __restrict__ A, const u16* __restrict__ Bt,
    float* __restrict__ C, int N, int K,
    const float* __restrict__ bias, const float* __restrict__ resid) {
    __shared__ __align__(16) u16 lds[2 * 24576];   // 96 KB

    int tid = threadIdx.x;
    int lane = tid & 63, wave = tid >> 6;          // 0..7
    int l15 = lane & 15, quad = lane >> 4;
    int wm = wave & 1, wn = wave >> 1;             // M half(128 rows), N quarter(32 cols)
    long tm0 = (long)blockIdx.y * 256, tn0 = (long)blockIdx.x * 128;
    int srow = lane >> 3;
    int scolw = ((lane & 7) ^ srow) * 8;           // T2 write-side
    int sk = l15 & 7;
    int ca0 = ((quad) ^ sk) * 8;                   // T2 read-side
    int ca1 = ((4 + quad) ^ sk) * 8;
    int steps = K >> 6;

    // half: 0=A rows 0-127 (2 ld/thr), 1=A rows 128-255 (2), 2=B rows 0-63 (1), 3=B rows 64-127 (1)
    auto STAGE = [&](int kt, int half, int buf) {
        long kk = (long)kt * 64;
        if (half < 2) {
            #pragma unroll
            for (int c = 0; c < 2; c++) {
                int chunk = wave * 2 + c;                    // 0..15
                int rloc = half * 128 + chunk * 8 + srow;
                gload_lds16(&A[(tm0 + rloc) * (long)K + kk + scolw],
                            &lds[buf * 24576 + half * 8192 + chunk * 512]);
            }
        } else {
            int rloc = (half - 2) * 64 + wave * 8 + srow;
            gload_lds16(&Bt[(tn0 + rloc) * (long)K + kk + scolw],
                        &lds[buf * 24576 + 16384 + (half - 2) * 4096 + wave * 512]);
        }
    };

    f32x4 acc[8][2] = {};
    bf16x8 af[4][2], bl[2], bh[2];

    STAGE(0, 0, 0); STAGE(0, 1, 0); STAGE(0, 2, 0); STAGE(0, 3, 0);   // 6 loads
    if (steps > 1) { STAGE(1, 2, 1); STAGE(1, 3, 1); }                 // 2 loads
    if (steps > 1) asm volatile("s_waitcnt vmcnt(2)" ::: "memory");
    else           asm volatile("s_waitcnt vmcnt(0)" ::: "memory");
    MBAR();

    for (int t = 0; t < steps; ++t) {
        int cur = t & 1;
        const u16* Ab = &lds[cur * 24576];
        const u16* Bb = &lds[cur * 24576 + 16384];
        bool pf1 = (t + 1 < steps), pf2 = (t + 2 < steps);

        // ph1: read af-mlo + bl; stage A-lo(t+1); MFMA acc[0:4][0]
        #pragma unroll
        for (int mt = 0; mt < 4; mt++) {
            int row = wm*128 + mt*16 + l15;
            af[mt][0] = *(const bf16x8*)&Ab[row * 64 + ca0];
            af[mt][1] = *(const bf16x8*)&Ab[row * 64 + ca1];
        }
        {
            int row = wn*32 + l15;
            bl[0] = *(const bf16x8*)&Bb[row * 64 + ca0];
            bl[1] = *(const bf16x8*)&Bb[row * 64 + ca1];
        }
        if (pf1) STAGE(t + 1, 0, cur ^ 1);
        MBAR();
        __builtin_amdgcn_s_setprio(1);
        #pragma unroll
        for (int mt = 0; mt < 4; mt++) {
            acc[mt][0] = __builtin_amdgcn_mfma_f32_16x16x32_bf16(af[mt][0], bl[0], acc[mt][0], 0,0,0);
            acc[mt][0] = __builtin_amdgcn_mfma_f32_16x16x32_bf16(af[mt][1], bl[1], acc[mt][0], 0,0,0);
        }
        __builtin_amdgcn_s_setprio(0);
        MBAR();

        // ph2: read bh; stage A-hi(t+1); MFMA acc[0:4][1]
        {
            int row = wn*32 + 16 + l15;
            bh[0] = *(const bf16x8*)&Bb[row * 64 + ca0];
            bh[1] = *(const bf16x8*)&Bb[row * 64 + ca1];
        }
        if (pf1) STAGE(t + 1, 1, cur ^ 1);
        MBAR();
        __builtin_amdgcn_s_setprio(1);
        #pragma unroll
        for (int mt = 0; mt < 4; mt++) {
            acc[mt][1] = __builtin_amdgcn_mfma_f32_16x16x32_bf16(af[mt][0], bh[0], acc[mt][1], 0,0,0);
            acc[mt][1] = __builtin_amdgcn_mfma_f32_16x16x32_bf16(af[mt][1], bh[1], acc[mt][1], 0,0,0);
        }
        __builtin_amdgcn_s_setprio(0);
        MBAR();

        // ph3: read af-mhi; stage B-lo(t+2); MFMA acc[4:8][1]
        #pragma unroll
        for (int mt = 0; mt < 4; mt++) {
            int row = wm*128 + 64 + mt*16 + l15;
            af[mt][0] = *(const bf16x8*)&Ab[row * 64 + ca0];
            af[mt][1] = *(const bf16x8*)&Ab[row * 64 + ca1];
        }
        if (pf2) STAGE(t + 2, 2, cur);
        MBAR();
        __builtin_amdgcn_s_setprio(1);
        #pragma unroll
        for (int mt = 0; mt < 4; mt++) {
            acc[4+mt][1] = __builtin_amdgcn_mfma_f32_16x16x32_bf16(af[mt][0], bh[0], acc[4+mt][1], 0,0,0);
            acc[4+mt][1] = __builtin_amdgcn_mfma_f32_16x16x32_bf16(af[mt][1], bh[1], acc[4+mt][1], 0,0,0);
        }
        __builtin_amdgcn_s_setprio(0);
        MBAR();

        // ph4: stage B-hi(t+2); MFMA acc[4:8][0] (bl held); tile-end counted vmcnt
        if (pf2) STAGE(t + 2, 3, cur);
        MBAR();
        __builtin_amdgcn_s_setprio(1);
        #pragma unroll
        for (int mt = 0; mt < 4; mt++) {
            acc[4+mt][0] = __builtin_amdgcn_mfma_f32_16x16x32_bf16(af[mt][0], bl[0], acc[4+mt][0], 0,0,0);
            acc[4+mt][0] = __builtin_amdgcn_mfma_f32_16x16x32_bf16(af[mt][1], bl[1], acc[4+mt][0], 0,0,0);
        }
        __builtin_amdgcn_s_setprio(0);
        if (pf2) asm volatile("s_waitcnt vmcnt(2)" ::: "memory");
        else     asm volatile("s_waitcnt vmcnt(0)" ::: "memory");
        MBAR();
    }

    #pragma unroll
    for (int mt = 0; mt < 8; mt++) {
        #pragma unroll
        for (int nt = 0; nt < 2; nt++) {
            #pragma unroll
            for (int i = 0; i < 4; i++) {
                long r = tm0 + wm*128 + mt*16 + quad*4 + i;
                int cn = (int)tn0 + wn*32 + nt*16 + l15;
                long idx = r * (long)N + cn;
                float bb = bias ? bias[cn] : 0.0f;
                C[idx] = acc[mt][nt][i] + bb + resid[idx];
            }
        }
    }
}

// ------------------------------------------------- attention
// R18 kernel RESTORED verbatim (measured 144.1-144.8 us). R19's QK-hoist
// pipeline regressed to 158: it moved kb's vmcnt wait INTO the iteration
// (between softmax and PV) instead of across the whole next iteration,
// and added 32 VGPR-moves/iter for score rotation. Keep R18: 2-wave
// blocks, balanced pair (j, 63-j), kbn prefetch consumed next-iteration.
#define LDP 72   // P row stride in u16

__global__ __launch_bounds__(128, 2) void attn_kernel(
    const u16* __restrict__ Q, const u16* __restrict__ Kg, const u16* __restrict__ Vt,
    const int* __restrict__ mask, u16* __restrict__ O) {
    __shared__ __align__(16) u16 Psm[2][32 * LDP];   // 9.2 KB
    int tid = threadIdx.x;
    int lane = tid & 63, wave = tid >> 6;            // 0..1
    int l15 = lane & 15, quad = lane >> 4;
    int bh = blockIdx.x; int b = bh >> 4, h = bh & 15;
    int j = blockIdx.y * 2 + wave;     // pair index 0..31
    long tokBase = (long)b * S_;
    const float SCL = 0.125f * 1.4426950408889634f;  // exp2 domain
    const float MMAX = 20.0f;                        // fixed softmax shift

    const bf16x8 ones = {16256,16256,16256,16256,16256,16256,16256,16256}; // bf16 1.0
    u16* Pw = Psm[wave];
    const int* mb = mask + b * S_;

    #pragma unroll
    for (int half = 0; half < 2; half++) {
        int t = half ? (63 - j) : j;   // q-tile index 0..63 (balanced pair)
        int q0 = t * 32;

        bf16x8 aq[2][2];
        #pragma unroll
        for (int mt = 0; mt < 2; mt++) {
            const u16* qptr = Q + (tokBase + q0 + mt*16 + l15) * D_ + h * 64;
            aq[mt][0] = *(const bf16x8*)(qptr + quad * 8);
            aq[mt][1] = *(const bf16x8*)(qptr + 32 + quad * 8);
        }

        f32x4 o[2][4] = {};
        f32x4 lacc[2] = {};
        int ktiles = t / 2 + 1;

        // prefetch kb for kt=0
        bf16x8 kb[4][2];
        #pragma unroll
        for (int nt = 0; nt < 4; nt++) {
            const u16* kp = Kg + (tokBase + nt*16 + l15) * D_ + h * 64;
            kb[nt][0] = *(const bf16x8*)(kp + quad * 8);
            kb[nt][1] = *(const bf16x8*)(kp + 32 + quad * 8);
        }

        for (int kt = 0; kt < ktiles; kt++) {
            int k0 = kt * 64;
            bf16x8 vb[4][2];
            #pragma unroll
            for (int d = 0; d < 4; d++) {
                const u16* vp = Vt + ((long)bh * 64 + d*16 + l15) * S_ + k0;
                vb[d][0] = *(const bf16x8*)(vp + quad * 8);
                vb[d][1] = *(const bf16x8*)(vp + 32 + quad * 8);
            }

            f32x4 s[2][4] = {};
            #pragma unroll
            for (int nt = 0; nt < 4; nt++) {
                s[0][nt] = __builtin_amdgcn_mfma_f32_16x16x32_bf16(aq[0][0], kb[nt][0], s[0][nt], 0,0,0);
                s[0][nt] = __builtin_amdgcn_mfma_f32_16x16x32_bf16(aq[0][1], kb[nt][1], s[0][nt], 0,0,0);
                s[1][nt] = __builtin_amdgcn_mfma_f32_16x16x32_bf16(aq[1][0], kb[nt][0], s[1][nt], 0,0,0);
                s[1][nt] = __builtin_amdgcn_mfma_f32_16x16x32_bf16(aq[1][1], kb[nt][1], s[1][nt], 0,0,0);
            }

            // prefetch kb(t+1) NOW — latency hides under the softmax below;
            // consumed at the TOP of the next iteration (full-iter slack).
            int k1 = (kt + 1 < ktiles) ? k0 + 64 : k0;
            bf16x8 kbn[4][2];
            #pragma unroll
            for (int nt = 0; nt < 4; nt++) {
                const u16* kp = Kg + (tokBase + k1 + nt*16 + l15) * D_ + h * 64;
                kbn[nt][0] = *(const bf16x8*)(kp + quad * 8);
                kbn[nt][1] = *(const bf16x8*)(kp + 32 + quad * 8);
            }

            int mk = 0;
            #pragma unroll
            for (int nt = 0; nt < 4; nt++)
                if (mb[k0 + nt*16 + l15] != 0) mk |= (1 << nt);

            #pragma unroll
            for (int mt = 0; mt < 2; mt++) {
                #pragma unroll
                for (int i = 0; i < 4; i++) {
                    int qq = q0 + mt*16 + quad*4 + i;
                    #pragma unroll
                    for (int nt = 0; nt < 4; nt++) {
                        int kc = k0 + nt*16 + l15;
                        float p = exp2f(fmaf(s[mt][nt][i], SCL, -MMAX));
                        p = (kc <= qq && ((mk >> nt) & 1)) ? p : 0.f;
                        Pw[(mt*16 + quad*4 + i) * LDP + nt*16 + l15] = f2bf(p);
                    }
                }
            }
            // same-wave P write -> read ordering (P is wave-private; LDS only —
            // the kbn global loads above stay in flight, they are vmcnt).
            asm volatile("s_waitcnt lgkmcnt(0)" ::: "memory");

            #pragma unroll
            for (int hv = 0; hv < 2; hv++) {
                bf16x8 ap0 = *(const bf16x8*)&Pw[l15 * LDP + hv*32 + quad*8];
                bf16x8 ap1 = *(const bf16x8*)&Pw[(16 + l15) * LDP + hv*32 + quad*8];
                #pragma unroll
                for (int d = 0; d < 4; d++) {
                    o[0][d] = __builtin_amdgcn_mfma_f32_16x16x32_bf16(ap0, vb[d][hv], o[0][d], 0,0,0);
                    o[1][d] = __builtin_amdgcn_mfma_f32_16x16x32_bf16(ap1, vb[d][hv], o[1][d], 0,0,0);
                }
                lacc[0] = __builtin_amdgcn_mfma_f32_16x16x32_bf16(ap0, ones, lacc[0], 0,0,0);
                lacc[1] = __builtin_amdgcn_mfma_f32_16x16x32_bf16(ap1, ones, lacc[1], 0,0,0);
            }

            // rotate prefetched K into place
            #pragma unroll
            for (int nt = 0; nt < 4; nt++) {
                kb[nt][0] = kbn[nt][0];
                kb[nt][1] = kbn[nt][1];
            }
        }

        #pragma unroll
        for (int mt = 0; mt < 2; mt++) {
            #pragma unroll
            for (int i = 0; i < 4; i++) {
                float inv = 1.f / lacc[mt][i];
                long r = tokBase + q0 + mt*16 + quad*4 + i;
                #pragma unroll
                for (int d = 0; d < 4; d++)
                    O[r * D_ + h*64 + d*16 + l15] = f2bf(o[mt][d][i] * inv);
            }
        }
    }
}

// ------------------------------------------------- launch
extern "C" void kernel_launch(void* const* d_in, const int* in_sizes, int n_in,
                              void* d_out, int out_size, void* d_ws, size_t ws_size,
                              hipStream_t stream) {
    const float* x    = (const float*)d_in[0];
    const int*   am   = (const int*)d_in[1];
    const float* ln1a = (const float*)d_in[2];
    const float* ln1b = (const float*)d_in[3];
    const float* ln2a = (const float*)d_in[4];
    const float* ln2b = (const float*)d_in[5];
    const float* wq   = (const float*)d_in[6];
    const float* wk   = (const float*)d_in[7];
    const float* wv   = (const float*)d_in[8];
    const float* wo   = (const float*)d_in[9];
    const float* w1   = (const float*)d_in[10];
    const float* b1   = (const float*)d_in[11];
    const float* w2   = (const float*)d_in[12];
    const float* b2   = (const float*)d_in[13];
    float* out = (float*)d_out;

    // Workspace: 72 MB, liveness-overlapped 16MB slots.
    char* ws = (char*)d_ws;
    const size_t MB16 = (size_t)16 * 1024 * 1024;
    u16* y1      = (u16*)(ws + 0 * MB16);
    u16* q       = (u16*)(ws + 1 * MB16);
    u16* k       = (u16*)(ws + 2 * MB16);
    u16* v       = (u16*)(ws + 3 * MB16);
    u16* wqt     = (u16*)(ws + 4 * MB16 + 0 * (size_t)D_ * D_ * 2);
    u16* wkt     = (u16*)(ws + 4 * MB16 + 1 * (size_t)D_ * D_ * 2);
    u16* wvt     = (u16*)(ws + 4 * MB16 + 2 * (size_t)D_ * D_ * 2);
    u16* wot     = (u16*)(ws + 4 * MB16 + 3 * (size_t)D_ * D_ * 2);
    u16* y2      = y1;
    u16* w1t     = q;
    u16* w2t     = q + (size_t)D_ * DFF;
    u16* h_full  = k;
    u16* ctx     = v;
    u16*   vt  = (u16*)d_out;                // d_out scratch; dead after attn
    float* x1f = out;

    dim3 tb(32, 8);
    transpose_f2b4<<<dim3(D_/32, D_/32, 4), tb, 0, stream>>>(
        wq, wk, wv, wo, wqt, wkt, wvt, wot, D_, D_);

    ln_kernel<<<NT, 256, 0, stream>>>(x, ln1a, ln1b, y1);

    // fused QKV: wqt/wkt/wvt are contiguous -> one [3072][1024] B matrix
    gemm8p<<<dim3(3*D_/BN2, NT/BM2), 512, 0, stream>>>(
        y1, wqt, q, k, v, 3*D_, D_, 0, nullptr);

    transpose_v<<<dim3(S_/32, 2, B_*H_), tb, 0, stream>>>(v, vt);

    attn_kernel<<<dim3(B_*H_, 16), 128, 0, stream>>>(q, k, vt, am, ctx);

    // Wo on the 8-phase 256x128 kernel (bias=nullptr -> resid-only epilogue)
    gemm8p_n128<<<dim3(D_/128, NT/256), 512, 0, stream>>>(
        ctx, wot, x1f, D_, D_, nullptr, x);

    transpose_f2b<<<dim3(DFF/32, D_/32), tb, 0, stream>>>(w1, w1t, D_, DFF);
    transpose_f2b<<<dim3(D_/32, DFF/32), tb, 0, stream>>>(w2, w2t, DFF, D_);

    ln_kernel<<<NT, 256, 0, stream>>>(x1f, ln2a, ln2b, y2);

    gemm8p<<<dim3(DFF/BN2, NT/BM2), 512, 0, stream>>>(
        y2, w1t, h_full, h_full, h_full, DFF, D_, 2, b1);

    // W2 on the 8-phase 256x128 kernel: grid (1024/128, 8192/256) = 256 blocks
    gemm8p_n128<<<dim3(D_/128, NT/256), 512, 0, stream>>>(
        h_full, w2t, out, D_, DFF, b2, x1f);
}

// Round 13
// 605.616 us; speedup vs baseline: 1.3734x; 1.0003x over previous
//
#include <hip/hip_runtime.h>
#include <math.h>

typedef unsigned short u16;
typedef unsigned int u32;
typedef __attribute__((ext_vector_type(4))) unsigned short u16x4;
typedef __attribute__((ext_vector_type(8))) short bf16x8;
typedef __attribute__((ext_vector_type(4))) float f32x4;

#define B_ 4
#define S_ 2048
#define D_ 1024
#define H_ 16
#define NT (B_*S_)
#define DFF 4096

static __device__ __forceinline__ float bf2f(u16 u) {
    return __uint_as_float(((u32)u) << 16);
}
static __device__ __forceinline__ u16 f2bf(float f) {
    u32 u = __float_as_uint(f);
    u32 r = (u + 0x7fffu + ((u >> 16) & 1u)) >> 16;
    return (u16)r;
}
// async 16B/lane global->LDS (LDS dest = wave-uniform base + lane*16)
static __device__ __forceinline__ void gload_lds16(const void* g, void* l) {
    __builtin_amdgcn_global_load_lds(
        (const __attribute__((address_space(1))) void*)g,
        (__attribute__((address_space(3))) void*)l, 16, 0, 0);
}
// tanh-form GELU via hw exp2 (validated R14: passed absmax 0.0625).
static __device__ __forceinline__ float gelu_fast(float x) {
    float x2 = x * x;
    float u = x * fmaf(0.044715f, x2, 1.0f);
    float e = exp2f(2.3022079f * u);
    float r = __builtin_amdgcn_rcpf(e + 1.0f);
    return x - x * r;
}

// raw barrier (no implicit vmcnt(0) drain, unlike __syncthreads) with
// compiler memory fences so C++ LDS reads can't be hoisted across it.
#define MBAR() do { asm volatile("" ::: "memory"); \
                    __builtin_amdgcn_s_barrier(); \
                    asm volatile("" ::: "memory"); } while (0)
// R21: scheduling fence. Rule #18: hipcc moves register-only MFMAs across
// asm "memory" fences (MFMAs touch no memory) — our 8-phase interleave was
// collapsing at codegen (MfmaUtil 18.6% = 2-phase regime despite 0 bank
// conflicts, verified-correct sync, template-identical structure). Pin the
// MFMA clusters between their barriers (m201-template placement; NOT
// m141's every-region pinning).
#define SBAR0() __builtin_amdgcn_sched_barrier(0)

// ------------------------------------------------- transpose fp32 -> bf16
__global__ void transpose_f2b4(const float* __restrict__ s0, const float* __restrict__ s1,
                               const float* __restrict__ s2, const float* __restrict__ s3,
                               u16* __restrict__ d0, u16* __restrict__ d1,
                               u16* __restrict__ d2, u16* __restrict__ d3,
                               int R, int C) {
    const float* in = s0; u16* out = d0;
    if (blockIdx.z == 1) { in = s1; out = d1; }
    else if (blockIdx.z == 2) { in = s2; out = d2; }
    else if (blockIdx.z == 3) { in = s3; out = d3; }
    __shared__ float t[32][33];
    int c0 = blockIdx.x * 32, r0 = blockIdx.y * 32;
    int x = threadIdx.x, y = threadIdx.y;
    #pragma unroll
    for (int i = 0; i < 4; i++)
        t[y + i*8][x] = in[(long)(r0 + y + i*8) * C + c0 + x];
    __syncthreads();
    #pragma unroll
    for (int i = 0; i < 4; i++)
        out[(long)(c0 + y + i*8) * R + r0 + x] = f2bf(t[x][y + i*8]);
}

__global__ void transpose_f2b(const float* __restrict__ in, u16* __restrict__ out,
                              int R, int C) {
    __shared__ float t[32][33];
    int c0 = blockIdx.x * 32, r0 = blockIdx.y * 32;
    int x = threadIdx.x, y = threadIdx.y;
    #pragma unroll
    for (int i = 0; i < 4; i++)
        t[y + i*8][x] = in[(long)(r0 + y + i*8) * C + c0 + x];
    __syncthreads();
    #pragma unroll
    for (int i = 0; i < 4; i++)
        out[(long)(c0 + y + i*8) * R + r0 + x] = f2bf(t[x][y + i*8]);
}

// V bf16 [B*S][D] -> Vt bf16 [B*H][64][S]. grid (S/32, 2, B*H), block (32,8)
__global__ void transpose_v(const u16* __restrict__ V, u16* __restrict__ Vt) {
    __shared__ u16 t[32][33];
    int z = blockIdx.z; int b = z >> 4, h = z & 15;
    int s0 = blockIdx.x * 32, d0 = blockIdx.y * 32;
    int x = threadIdx.x, y = threadIdx.y;
    const u16* in = V + ((long)b * S_ + s0) * D_ + h * 64 + d0;
    #pragma unroll
    for (int i = 0; i < 4; i++)
        t[y + i*8][x] = in[(long)(y + i*8) * D_ + x];
    __syncthreads();
    u16* out = Vt + ((long)z * 64 + d0) * S_ + s0;
    #pragma unroll
    for (int i = 0; i < 4; i++)
        out[(long)(y + i*8) * S_ + x] = t[x][y + i*8];
}

// ------------------------------------------------- layernorm (fp32 in, bf16 out)
__global__ __launch_bounds__(256) void ln_kernel(
    const float* __restrict__ X, const float* __restrict__ alpha,
    const float* __restrict__ beta, u16* __restrict__ Y) {
    int row = blockIdx.x, tid = threadIdx.x;
    float4 xv = ((const float4*)(X + (long)row * D_))[tid];
    float v[4] = {xv.x, xv.y, xv.z, xv.w};
    float s = 0.f, ss = 0.f;
    #pragma unroll
    for (int i = 0; i < 4; i++) { s += v[i]; ss += v[i]*v[i]; }
    #pragma unroll
    for (int off = 32; off >= 1; off >>= 1) {
        s += __shfl_xor(s, off);
        ss += __shfl_xor(ss, off);
    }
    __shared__ float red[8];
    __shared__ float stats[2];
    int w = tid >> 6;
    if ((tid & 63) == 0) { red[w] = s; red[4 + w] = ss; }
    __syncthreads();
    if (tid == 0) {
        float S = red[0] + red[1] + red[2] + red[3];
        float SS = red[4] + red[5] + red[6] + red[7];
        float mean = S * (1.f / D_);
        float var = SS * (1.f / D_) - mean * mean;
        stats[0] = mean; stats[1] = rsqrtf(var + 1e-5f);
    }
    __syncthreads();
    float mean = stats[0], rstd = stats[1];
    float4 av = ((const float4*)alpha)[tid];
    float4 bv = ((const float4*)beta)[tid];
    u16x4 o;
    o[0] = f2bf((v[0] - mean) * rstd * av.x + bv.x);
    o[1] = f2bf((v[1] - mean) * rstd * av.y + bv.y);
    o[2] = f2bf((v[2] - mean) * rstd * av.z + bv.z);
    o[3] = f2bf((v[3] - mean) * rstd * av.w + bv.w);
    *(u16x4*)(Y + (long)row * D_ + tid * 4) = o;
}

// ------------------------------------------------- GEMM 256^2 8-phase (QKV fused, W1)
// R16 schedule + R21 sched_barrier(0) MFMA-cluster pinning.
#define BM2 256
#define BN2 256
#define BK2 64

__global__ __launch_bounds__(512, 2) void gemm8p(
    const u16* __restrict__ A, const u16* __restrict__ Bt,
    u16* __restrict__ C0, u16* __restrict__ C1, u16* __restrict__ C2,
    int N, int K, int mode, const float* __restrict__ bias) {
    __shared__ __align__(16) u16 lds[2 * 32768];   // 128 KB

    int tid = threadIdx.x;
    int lane = tid & 63, wave = tid >> 6;          // wave 0..7
    int l15 = lane & 15, quad = lane >> 4;
    int wm = wave & 1, wn = wave >> 1;             // M half, N quarter
    long tm0 = (long)blockIdx.y * BM2, tn0 = (long)blockIdx.x * BN2;
    int srow = lane >> 3;
    int scolw = ((lane & 7) ^ srow) * 8;           // T2 write-side inverse swizzle
    int sk = l15 & 7;
    int ca0 = ((quad) ^ sk) * 8;                   // T2 read-side
    int ca1 = ((4 + quad) ^ sk) * 8;
    int steps = K >> 6;

    auto STAGE = [&](int kt, int half, int buf) {
        long kk = (long)kt * BK2;
        #pragma unroll
        for (int c = 0; c < 2; c++) {
            int chunk = wave * 2 + c;                       // 0..15
            int rloc = (half & 1) * 128 + chunk * 8 + srow; // row in tile
            const u16* g = (half < 2)
                ? &A [(tm0 + rloc) * (long)K + kk + scolw]
                : &Bt[(tn0 + rloc) * (long)K + kk + scolw];
            u16* l = &lds[buf * 32768 + (half >= 2 ? 16384 : 0)
                          + (half & 1) * 8192 + chunk * 512];
            gload_lds16(g, l);
        }
    };

    f32x4 acc[8][4] = {};
    bf16x8 af[4][2], bl[2][2], bh[2][2];

    STAGE(0, 0, 0); STAGE(0, 1, 0); STAGE(0, 2, 0); STAGE(0, 3, 0);
    if (steps > 1) { STAGE(1, 2, 1); STAGE(1, 3, 1); }
    if (steps > 1) asm volatile("s_waitcnt vmcnt(4)" ::: "memory");
    else           asm volatile("s_waitcnt vmcnt(0)" ::: "memory");
    MBAR();

    for (int t = 0; t < steps; ++t) {
        int cur = t & 1;
        const u16* Ab = &lds[cur * 32768];
        const u16* Bb = &lds[cur * 32768 + 16384];
        bool pf1 = (t + 1 < steps), pf2 = (t + 2 < steps);

        // ph1
        #pragma unroll
        for (int mt = 0; mt < 4; mt++) {
            int row = wm*128 + mt*16 + l15;
            af[mt][0] = *(const bf16x8*)&Ab[row * BK2 + ca0];
            af[mt][1] = *(const bf16x8*)&Ab[row * BK2 + ca1];
        }
        #pragma unroll
        for (int nt = 0; nt < 2; nt++) {
            int row = wn*64 + nt*16 + l15;
            bl[nt][0] = *(const bf16x8*)&Bb[row * BK2 + ca0];
            bl[nt][1] = *(const bf16x8*)&Bb[row * BK2 + ca1];
        }
        if (pf1) STAGE(t + 1, 0, cur ^ 1);
        MBAR();
        SBAR0();
        __builtin_amdgcn_s_setprio(1);
        #pragma unroll
        for (int mt = 0; mt < 4; mt++)
            #pragma unroll
            for (int nt = 0; nt < 2; nt++) {
                acc[mt][nt] = __builtin_amdgcn_mfma_f32_16x16x32_bf16(af[mt][0], bl[nt][0], acc[mt][nt], 0,0,0);
                acc[mt][nt] = __builtin_amdgcn_mfma_f32_16x16x32_bf16(af[mt][1], bl[nt][1], acc[mt][nt], 0,0,0);
            }
        __builtin_amdgcn_s_setprio(0);
        SBAR0();
        MBAR();

        // ph2
        #pragma unroll
        for (int nt = 0; nt < 2; nt++) {
            int row = wn*64 + (2+nt)*16 + l15;
            bh[nt][0] = *(const bf16x8*)&Bb[row * BK2 + ca0];
            bh[nt][1] = *(const bf16x8*)&Bb[row * BK2 + ca1];
        }
        if (pf1) STAGE(t + 1, 1, cur ^ 1);
        MBAR();
        SBAR0();
        __builtin_amdgcn_s_setprio(1);
        #pragma unroll
        for (int mt = 0; mt < 4; mt++)
            #pragma unroll
            for (int nt = 0; nt < 2; nt++) {
                acc[mt][2+nt] = __builtin_amdgcn_mfma_f32_16x16x32_bf16(af[mt][0], bh[nt][0], acc[mt][2+nt], 0,0,0);
                acc[mt][2+nt] = __builtin_amdgcn_mfma_f32_16x16x32_bf16(af[mt][1], bh[nt][1], acc[mt][2+nt], 0,0,0);
            }
        __builtin_amdgcn_s_setprio(0);
        SBAR0();
        MBAR();

        // ph3
        #pragma unroll
        for (int mt = 0; mt < 4; mt++) {
            int row = wm*128 + 64 + mt*16 + l15;
            af[mt][0] = *(const bf16x8*)&Ab[row * BK2 + ca0];
            af[mt][1] = *(const bf16x8*)&Ab[row * BK2 + ca1];
        }
        if (pf2) STAGE(t + 2, 2, cur);
        MBAR();
        SBAR0();
        __builtin_amdgcn_s_setprio(1);
        #pragma unroll
        for (int mt = 0; mt < 4; mt++)
            #pragma unroll
            for (int nt = 0; nt < 2; nt++) {
                acc[4+mt][2+nt] = __builtin_amdgcn_mfma_f32_16x16x32_bf16(af[mt][0], bh[nt][0], acc[4+mt][2+nt], 0,0,0);
                acc[4+mt][2+nt] = __builtin_amdgcn_mfma_f32_16x16x32_bf16(af[mt][1], bh[nt][1], acc[4+mt][2+nt], 0,0,0);
            }
        __builtin_amdgcn_s_setprio(0);
        SBAR0();
        MBAR();

        // ph4
        if (pf2) STAGE(t + 2, 3, cur);
        MBAR();
        SBAR0();
        __builtin_amdgcn_s_setprio(1);
        #pragma unroll
        for (int mt = 0; mt < 4; mt++)
            #pragma unroll
            for (int nt = 0; nt < 2; nt++) {
                acc[4+mt][nt] = __builtin_amdgcn_mfma_f32_16x16x32_bf16(af[mt][0], bl[nt][0], acc[4+mt][nt], 0,0,0);
                acc[4+mt][nt] = __builtin_amdgcn_mfma_f32_16x16x32_bf16(af[mt][1], bl[nt][1], acc[4+mt][nt], 0,0,0);
            }
        __builtin_amdgcn_s_setprio(0);
        SBAR0();
        if (pf2) asm volatile("s_waitcnt vmcnt(4)" ::: "memory");
        else     asm volatile("s_waitcnt vmcnt(0)" ::: "memory");
        MBAR();
    }

    #pragma unroll
    for (int mt = 0; mt < 8; mt++) {
        #pragma unroll
        for (int nt = 0; nt < 4; nt++) {
            #pragma unroll
            for (int i = 0; i < 4; i++) {
                long r = tm0 + wm*128 + mt*16 + quad*4 + i;
                int cn = (int)tn0 + wn*64 + nt*16 + l15;
                float val = acc[mt][nt][i];
                if (mode == 0) {           // fused QKV: route to q/k/v slabs
                    int mi = cn >> 10;
                    int col = cn & 1023;
                    u16* base = (mi == 0) ? C0 : (mi == 1 ? C1 : C2);
                    base[r * 1024 + col] = f2bf(val);
                } else {                   // mode 2: bias + GELU -> bf16
                    val += bias[cn];
                    C0[r * (long)N + cn] = f2bf(gelu_fast(val));
                }
            }
        }
    }
}

// ------------------------------------------------- GEMM 256x128 8-phase (Wo, W2)
// R19 schedule + R21 sched_barrier(0) MFMA-cluster pinning.
__global__ __launch_bounds__(512, 2) void gemm8p_n128(
    const u16* __restrict__ A, const u16* __restrict__ Bt,
    float* __restrict__ C, int N, int K,
    const float* __restrict__ bias, const float* __restrict__ resid) {
    __shared__ __align__(16) u16 lds[2 * 24576];   // 96 KB

    int tid = threadIdx.x;
    int lane = tid & 63, wave = tid >> 6;          // 0..7
    int l15 = lane & 15, quad = lane >> 4;
    int wm = wave & 1, wn = wave >> 1;             // M half(128 rows), N quarter(32 cols)
    long tm0 = (long)blockIdx.y * 256, tn0 = (long)blockIdx.x * 128;
    int srow = lane >> 3;
    int scolw = ((lane & 7) ^ srow) * 8;           // T2 write-side
    int sk = l15 & 7;
    int ca0 = ((quad) ^ sk) * 8;                   // T2 read-side
    int ca1 = ((4 + quad) ^ sk) * 8;
    int steps = K >> 6;

    // half: 0=A rows 0-127 (2 ld/thr), 1=A rows 128-255 (2), 2=B rows 0-63 (1), 3=B rows 64-127 (1)
    auto STAGE = [&](int kt, int half, int buf) {
        long kk = (long)kt * 64;
        if (half < 2) {
            #pragma unroll
            for (int c = 0; c < 2; c++) {
                int chunk = wave * 2 + c;                    // 0..15
                int rloc = half * 128 + chunk * 8 + srow;
                gload_lds16(&A[(tm0 + rloc) * (long)K + kk + scolw],
                            &lds[buf * 24576 + half * 8192 + chunk * 512]);
            }
        } else {
            int rloc = (half - 2) * 64 + wave * 8 + srow;
            gload_lds16(&Bt[(tn0 + rloc) * (long)K + kk + scolw],
                        &lds[buf * 24576 + 16384 + (half - 2) * 4096 + wave * 512]);
        }
    };

    f32x4 acc[8][2] = {};
    bf16x8 af[4][2], bl[2], bh[2];

    STAGE(0, 0, 0); STAGE(0, 1, 0); STAGE(0, 2, 0); STAGE(0, 3, 0);   // 6 loads
    if (steps > 1) { STAGE(1, 2, 1); STAGE(1, 3, 1); }                 // 2 loads
    if (steps > 1) asm volatile("s_waitcnt vmcnt(2)" ::: "memory");
    else           asm volatile("s_waitcnt vmcnt(0)" ::: "memory");
    MBAR();

    for (int t = 0; t < steps; ++t) {
        int cur = t & 1;
        const u16* Ab = &lds[cur * 24576];
        const u16* Bb = &lds[cur * 24576 + 16384];
        bool pf1 = (t + 1 < steps), pf2 = (t + 2 < steps);

        // ph1: read af-mlo + bl; stage A-lo(t+1); MFMA acc[0:4][0]
        #pragma unroll
        for (int mt = 0; mt < 4; mt++) {
            int row = wm*128 + mt*16 + l15;
            af[mt][0] = *(const bf16x8*)&Ab[row * 64 + ca0];
            af[mt][1] = *(const bf16x8*)&Ab[row * 64 + ca1];
        }
        {
            int row = wn*32 + l15;
            bl[0] = *(const bf16x8*)&Bb[row * 64 + ca0];
            bl[1] = *(const bf16x8*)&Bb[row * 64 + ca1];
        }
        if (pf1) STAGE(t + 1, 0, cur ^ 1);
        MBAR();
        SBAR0();
        __builtin_amdgcn_s_setprio(1);
        #pragma unroll
        for (int mt = 0; mt < 4; mt++) {
            acc[mt][0] = __builtin_amdgcn_mfma_f32_16x16x32_bf16(af[mt][0], bl[0], acc[mt][0], 0,0,0);
            acc[mt][0] = __builtin_amdgcn_mfma_f32_16x16x32_bf16(af[mt][1], bl[1], acc[mt][0], 0,0,0);
        }
        __builtin_amdgcn_s_setprio(0);
        SBAR0();
        MBAR();

        // ph2: read bh; stage A-hi(t+1); MFMA acc[0:4][1]
        {
            int row = wn*32 + 16 + l15;
            bh[0] = *(const bf16x8*)&Bb[row * 64 + ca0];
            bh[1] = *(const bf16x8*)&Bb[row * 64 + ca1];
        }
        if (pf1) STAGE(t + 1, 1, cur ^ 1);
        MBAR();
        SBAR0();
        __builtin_amdgcn_s_setprio(1);
        #pragma unroll
        for (int mt = 0; mt < 4; mt++) {
            acc[mt][1] = __builtin_amdgcn_mfma_f32_16x16x32_bf16(af[mt][0], bh[0], acc[mt][1], 0,0,0);
            acc[mt][1] = __builtin_amdgcn_mfma_f32_16x16x32_bf16(af[mt][1], bh[1], acc[mt][1], 0,0,0);
        }
        __builtin_amdgcn_s_setprio(0);
        SBAR0();
        MBAR();

        // ph3: read af-mhi; stage B-lo(t+2); MFMA acc[4:8][1]
        #pragma unroll
        for (int mt = 0; mt < 4; mt++) {
            int row = wm*128 + 64 + mt*16 + l15;
            af[mt][0] = *(const bf16x8*)&Ab[row * 64 + ca0];
            af[mt][1] = *(const bf16x8*)&Ab[row * 64 + ca1];
        }
        if (pf2) STAGE(t + 2, 2, cur);
        MBAR();
        SBAR0();
        __builtin_amdgcn_s_setprio(1);
        #pragma unroll
        for (int mt = 0; mt < 4; mt++) {
            acc[4+mt][1] = __builtin_amdgcn_mfma_f32_16x16x32_bf16(af[mt][0], bh[0], acc[4+mt][1], 0,0,0);
            acc[4+mt][1] = __builtin_amdgcn_mfma_f32_16x16x32_bf16(af[mt][1], bh[1], acc[4+mt][1], 0,0,0);
        }
        __builtin_amdgcn_s_setprio(0);
        SBAR0();
        MBAR();

        // ph4: stage B-hi(t+2); MFMA acc[4:8][0] (bl held); tile-end counted vmcnt
        if (pf2) STAGE(t + 2, 3, cur);
        MBAR();
        SBAR0();
        __builtin_amdgcn_s_setprio(1);
        #pragma unroll
        for (int mt = 0; mt < 4; mt++) {
            acc[4+mt][0] = __builtin_amdgcn_mfma_f32_16x16x32_bf16(af[mt][0], bl[0], acc[4+mt][0], 0,0,0);
            acc[4+mt][0] = __builtin_amdgcn_mfma_f32_16x16x32_bf16(af[mt][1], bl[1], acc[4+mt][0], 0,0,0);
        }
        __builtin_amdgcn_s_setprio(0);
        SBAR0();
        if (pf2) asm volatile("s_waitcnt vmcnt(2)" ::: "memory");
        else     asm volatile("s_waitcnt vmcnt(0)" ::: "memory");
        MBAR();
    }

    #pragma unroll
    for (int mt = 0; mt < 8; mt++) {
        #pragma unroll
        for (int nt = 0; nt < 2; nt++) {
            #pragma unroll
            for (int i = 0; i < 4; i++) {
                long r = tm0 + wm*128 + mt*16 + quad*4 + i;
                int cn = (int)tn0 + wn*32 + nt*16 + l15;
                long idx = r * (long)N + cn;
                float bb = bias ? bias[cn] : 0.0f;
                C[idx] = acc[mt][nt][i] + bb + resid[idx];
            }
        }
    }
}

// ------------------------------------------------- attention
// R18 kernel (KEEP verbatim, 144-148 us): 2-wave blocks, balanced pair
// (j, 63-j), kbn prefetch consumed next-iteration. R19 pipeline regressed;
// occupancy levers (R12/R13/R18) all null — do not re-attempt without a
// structural rewrite (swapped-QK in-register softmax).
#define LDP 72   // P row stride in u16

__global__ __launch_bounds__(128, 2) void attn_kernel(
    const u16* __restrict__ Q, const u16* __restrict__ Kg, const u16* __restrict__ Vt,
    const int* __restrict__ mask, u16* __restrict__ O) {
    __shared__ __align__(16) u16 Psm[2][32 * LDP];   // 9.2 KB
    int tid = threadIdx.x;
    int lane = tid & 63, wave = tid >> 6;            // 0..1
    int l15 = lane & 15, quad = lane >> 4;
    int bh = blockIdx.x; int b = bh >> 4, h = bh & 15;
    int j = blockIdx.y * 2 + wave;     // pair index 0..31
    long tokBase = (long)b * S_;
    const float SCL = 0.125f * 1.4426950408889634f;  // exp2 domain
    const float MMAX = 20.0f;                        // fixed softmax shift

    const bf16x8 ones = {16256,16256,16256,16256,16256,16256,16256,16256}; // bf16 1.0
    u16* Pw = Psm[wave];
    const int* mb = mask + b * S_;

    #pragma unroll
    for (int half = 0; half < 2; half++) {
        int t = half ? (63 - j) : j;   // q-tile index 0..63 (balanced pair)
        int q0 = t * 32;

        bf16x8 aq[2][2];
        #pragma unroll
        for (int mt = 0; mt < 2; mt++) {
            const u16* qptr = Q + (tokBase + q0 + mt*16 + l15) * D_ + h * 64;
            aq[mt][0] = *(const bf16x8*)(qptr + quad * 8);
            aq[mt][1] = *(const bf16x8*)(qptr + 32 + quad * 8);
        }

        f32x4 o[2][4] = {};
        f32x4 lacc[2] = {};
        int ktiles = t / 2 + 1;

        // prefetch kb for kt=0
        bf16x8 kb[4][2];
        #pragma unroll
        for (int nt = 0; nt < 4; nt++) {
            const u16* kp = Kg + (tokBase + nt*16 + l15) * D_ + h * 64;
            kb[nt][0] = *(const bf16x8*)(kp + quad * 8);
            kb[nt][1] = *(const bf16x8*)(kp + 32 + quad * 8);
        }

        for (int kt = 0; kt < ktiles; kt++) {
            int k0 = kt * 64;
            bf16x8 vb[4][2];
            #pragma unroll
            for (int d = 0; d < 4; d++) {
                const u16* vp = Vt + ((long)bh * 64 + d*16 + l15) * S_ + k0;
                vb[d][0] = *(const bf16x8*)(vp + quad * 8);
                vb[d][1] = *(const bf16x8*)(vp + 32 + quad * 8);
            }

            f32x4 s[2][4] = {};
            #pragma unroll
            for (int nt = 0; nt < 4; nt++) {
                s[0][nt] = __builtin_amdgcn_mfma_f32_16x16x32_bf16(aq[0][0], kb[nt][0], s[0][nt], 0,0,0);
                s[0][nt] = __builtin_amdgcn_mfma_f32_16x16x32_bf16(aq[0][1], kb[nt][1], s[0][nt], 0,0,0);
                s[1][nt] = __builtin_amdgcn_mfma_f32_16x16x32_bf16(aq[1][0], kb[nt][0], s[1][nt], 0,0,0);
                s[1][nt] = __builtin_amdgcn_mfma_f32_16x16x32_bf16(aq[1][1], kb[nt][1], s[1][nt], 0,0,0);
            }

            // prefetch kb(t+1) NOW — latency hides under the softmax below;
            // consumed at the TOP of the next iteration (full-iter slack).
            int k1 = (kt + 1 < ktiles) ? k0 + 64 : k0;
            bf16x8 kbn[4][2];
            #pragma unroll
            for (int nt = 0; nt < 4; nt++) {
                const u16* kp = Kg + (tokBase + k1 + nt*16 + l15) * D_ + h * 64;
                kbn[nt][0] = *(const bf16x8*)(kp + quad * 8);
                kbn[nt][1] = *(const bf16x8*)(kp + 32 + quad * 8);
            }

            int mk = 0;
            #pragma unroll
            for (int nt = 0; nt < 4; nt++)
                if (mb[k0 + nt*16 + l15] != 0) mk |= (1 << nt);

            #pragma unroll
            for (int mt = 0; mt < 2; mt++) {
                #pragma unroll
                for (int i = 0; i < 4; i++) {
                    int qq = q0 + mt*16 + quad*4 + i;
                    #pragma unroll
                    for (int nt = 0; nt < 4; nt++) {
                        int kc = k0 + nt*16 + l15;
                        float p = exp2f(fmaf(s[mt][nt][i], SCL, -MMAX));
                        p = (kc <= qq && ((mk >> nt) & 1)) ? p : 0.f;
                        Pw[(mt*16 + quad*4 + i) * LDP + nt*16 + l15] = f2bf(p);
                    }
                }
            }
            // same-wave P write -> read ordering (P is wave-private; LDS only —
            // the kbn global loads above stay in flight, they are vmcnt).
            asm volatile("s_waitcnt lgkmcnt(0)" ::: "memory");

            #pragma unroll
            for (int hv = 0; hv < 2; hv++) {
                bf16x8 ap0 = *(const bf16x8*)&Pw[l15 * LDP + hv*32 + quad*8];
                bf16x8 ap1 = *(const bf16x8*)&Pw[(16 + l15) * LDP + hv*32 + quad*8];
                #pragma unroll
                for (int d = 0; d < 4; d++) {
                    o[0][d] = __builtin_amdgcn_mfma_f32_16x16x32_bf16(ap0, vb[d][hv], o[0][d], 0,0,0);
                    o[1][d] = __builtin_amdgcn_mfma_f32_16x16x32_bf16(ap1, vb[d][hv], o[1][d], 0,0,0);
                }
                lacc[0] = __builtin_amdgcn_mfma_f32_16x16x32_bf16(ap0, ones, lacc[0], 0,0,0);
                lacc[1] = __builtin_amdgcn_mfma_f32_16x16x32_bf16(ap1, ones, lacc[1], 0,0,0);
            }

            // rotate prefetched K into place
            #pragma unroll
            for (int nt = 0; nt < 4; nt++) {
                kb[nt][0] = kbn[nt][0];
                kb[nt][1] = kbn[nt][1];
            }
        }

        #pragma unroll
        for (int mt = 0; mt < 2; mt++) {
            #pragma unroll
            for (int i = 0; i < 4; i++) {
                float inv = 1.f / lacc[mt][i];
                long r = tokBase + q0 + mt*16 + quad*4 + i;
                #pragma unroll
                for (int d = 0; d < 4; d++)
                    O[r * D_ + h*64 + d*16 + l15] = f2bf(o[mt][d][i] * inv);
            }
        }
    }
}

// ------------------------------------------------- launch
extern "C" void kernel_launch(void* const* d_in, const int* in_sizes, int n_in,
                              void* d_out, int out_size, void* d_ws, size_t ws_size,
                              hipStream_t stream) {
    const float* x    = (const float*)d_in[0];
    const int*   am   = (const int*)d_in[1];
    const float* ln1a = (const float*)d_in[2];
    const float* ln1b = (const float*)d_in[3];
    const float* ln2a = (const float*)d_in[4];
    const float* ln2b = (const float*)d_in[5];
    const float* wq   = (const float*)d_in[6];
    const float* wk   = (const float*)d_in[7];
    const float* wv   = (const float*)d_in[8];
    const float* wo   = (const float*)d_in[9];
    const float* w1   = (const float*)d_in[10];
    const float* b1   = (const float*)d_in[11];
    const float* w2   = (const float*)d_in[12];
    const float* b2   = (const float*)d_in[13];
    float* out = (float*)d_out;

    // Workspace: 72 MB, liveness-overlapped 16MB slots.
    char* ws = (char*)d_ws;
    const size_t MB16 = (size_t)16 * 1024 * 1024;
    u16* y1      = (u16*)(ws + 0 * MB16);
    u16* q       = (u16*)(ws + 1 * MB16);
    u16* k       = (u16*)(ws + 2 * MB16);
    u16* v       = (u16*)(ws + 3 * MB16);
    u16* wqt     = (u16*)(ws + 4 * MB16 + 0 * (size_t)D_ * D_ * 2);
    u16* wkt     = (u16*)(ws + 4 * MB16 + 1 * (size_t)D_ * D_ * 2);
    u16* wvt     = (u16*)(ws + 4 * MB16 + 2 * (size_t)D_ * D_ * 2);
    u16* wot     = (u16*)(ws + 4 * MB16 + 3 * (size_t)D_ * D_ * 2);
    u16* y2      = y1;
    u16* w1t     = q;
    u16* w2t     = q + (size_t)D_ * DFF;
    u16* h_full  = k;
    u16* ctx     = v;
    u16*   vt  = (u16*)d_out;                // d_out scratch; dead after attn
    float* x1f = out;

    dim3 tb(32, 8);
    transpose_f2b4<<<dim3(D_/32, D_/32, 4), tb, 0, stream>>>(
        wq, wk, wv, wo, wqt, wkt, wvt, wot, D_, D_);

    ln_kernel<<<NT, 256, 0, stream>>>(x, ln1a, ln1b, y1);

    // fused QKV: wqt/wkt/wvt are contiguous -> one [3072][1024] B matrix
    gemm8p<<<dim3(3*D_/BN2, NT/BM2), 512, 0, stream>>>(
        y1, wqt, q, k, v, 3*D_, D_, 0, nullptr);

    transpose_v<<<dim3(S_/32, 2, B_*H_), tb, 0, stream>>>(v, vt);

    attn_kernel<<<dim3(B_*H_, 16), 128, 0, stream>>>(q, k, vt, am, ctx);

    // Wo on the 8-phase 256x128 kernel (bias=nullptr -> resid-only epilogue)
    gemm8p_n128<<<dim3(D_/128, NT/256), 512, 0, stream>>>(
        ctx, wot, x1f, D_, D_, nullptr, x);

    transpose_f2b<<<dim3(DFF/32, D_/32), tb, 0, stream>>>(w1, w1t, D_, DFF);
    transpose_f2b<<<dim3(D_/32, DFF/32), tb, 0, stream>>>(w2, w2t, DFF, D_);

    ln_kernel<<<NT, 256, 0, stream>>>(x1f, ln2a, ln2b, y2);

    gemm8p<<<dim3(DFF/BN2, NT/BM2), 512, 0, stream>>>(
        y2, w1t, h_full, h_full, h_full, DFF, D_, 2, b1);

    // W2 on the 8-phase 256x128 kernel: grid (1024/128, 8192/256) = 256 blocks
    gemm8p_n128<<<dim3(D_/128, NT/256), 512, 0, stream>>>(
        h_full, w2t, out, D_, DFF, b2, x1f);
}

// Round 17
// 605.185 us; speedup vs baseline: 1.3743x; 1.0007x over previous
//
#include <hip/hip_runtime.h>
#include <math.h>

typedef unsigned short u16;
typedef unsigned int u32;
typedef __attribute__((ext_vector_type(4))) unsigned short u16x4;
typedef __attribute__((ext_vector_type(8))) short bf16x8;
typedef __attribute__((ext_vector_type(4))) float f32x4;

#define B_ 4
#define S_ 2048
#define D_ 1024
#define H_ 16
#define NT (B_*S_)
#define DFF 4096

static __device__ __forceinline__ float bf2f(u16 u) {
    return __uint_as_float(((u32)u) << 16);
}
static __device__ __forceinline__ u16 f2bf(float f) {
    u32 u = __float_as_uint(f);
    u32 r = (u + 0x7fffu + ((u >> 16) & 1u)) >> 16;
    return (u16)r;
}
// packed f32 pair -> bf16x2 (RNE), gfx950 hw op (no builtin; T12 recipe)
static __device__ __forceinline__ u32 cvtpk(float lo, float hi) {
    u32 r;
    asm("v_cvt_pk_bf16_f32 %0, %1, %2" : "=v"(r) : "v"(lo), "v"(hi));
    return r;
}
// async 16B/lane global->LDS (LDS dest = wave-uniform base + lane*16)
static __device__ __forceinline__ void gload_lds16(const void* g, void* l) {
    __builtin_amdgcn_global_load_lds(
        (const __attribute__((address_space(1))) void*)g,
        (__attribute__((address_space(3))) void*)l, 16, 0, 0);
}
// tanh-form GELU via hw exp2 (validated R14: passed absmax 0.0625).
static __device__ __forceinline__ float gelu_fast(float x) {
    float x2 = x * x;
    float u = x * fmaf(0.044715f, x2, 1.0f);
    float e = exp2f(2.3022079f * u);
    float r = __builtin_amdgcn_rcpf(e + 1.0f);
    return x - x * r;
}

// raw barrier (no implicit vmcnt(0) drain, unlike __syncthreads) with
// compiler memory fences so C++ LDS reads can't be hoisted across it.
#define MBAR() do { asm volatile("" ::: "memory"); \
                    __builtin_amdgcn_s_barrier(); \
                    asm volatile("" ::: "memory"); } while (0)
#define SBAR0() __builtin_amdgcn_sched_barrier(0)

// ------------------------------------------------- transpose fp32 -> bf16
__global__ void transpose_f2b4(const float* __restrict__ s0, const float* __restrict__ s1,
                               const float* __restrict__ s2, const float* __restrict__ s3,
                               u16* __restrict__ d0, u16* __restrict__ d1,
                               u16* __restrict__ d2, u16* __restrict__ d3,
                               int R, int C) {
    const float* in = s0; u16* out = d0;
    if (blockIdx.z == 1) { in = s1; out = d1; }
    else if (blockIdx.z == 2) { in = s2; out = d2; }
    else if (blockIdx.z == 3) { in = s3; out = d3; }
    __shared__ float t[32][33];
    int c0 = blockIdx.x * 32, r0 = blockIdx.y * 32;
    int x = threadIdx.x, y = threadIdx.y;
    #pragma unroll
    for (int i = 0; i < 4; i++)
        t[y + i*8][x] = in[(long)(r0 + y + i*8) * C + c0 + x];
    __syncthreads();
    #pragma unroll
    for (int i = 0; i < 4; i++)
        out[(long)(c0 + y + i*8) * R + r0 + x] = f2bf(t[x][y + i*8]);
}

__global__ void transpose_f2b(const float* __restrict__ in, u16* __restrict__ out,
                              int R, int C) {
    __shared__ float t[32][33];
    int c0 = blockIdx.x * 32, r0 = blockIdx.y * 32;
    int x = threadIdx.x, y = threadIdx.y;
    #pragma unroll
    for (int i = 0; i < 4; i++)
        t[y + i*8][x] = in[(long)(r0 + y + i*8) * C + c0 + x];
    __syncthreads();
    #pragma unroll
    for (int i = 0; i < 4; i++)
        out[(long)(c0 + y + i*8) * R + r0 + x] = f2bf(t[x][y + i*8]);
}

// V bf16 [B*S][D] -> Vt bf16 [B*H][64][S]. grid (S/32, 2, B*H), block (32,8)
__global__ void transpose_v(const u16* __restrict__ V, u16* __restrict__ Vt) {
    __shared__ u16 t[32][33];
    int z = blockIdx.z; int b = z >> 4, h = z & 15;
    int s0 = blockIdx.x * 32, d0 = blockIdx.y * 32;
    int x = threadIdx.x, y = threadIdx.y;
    const u16* in = V + ((long)b * S_ + s0) * D_ + h * 64 + d0;
    #pragma unroll
    for (int i = 0; i < 4; i++)
        t[y + i*8][x] = in[(long)(y + i*8) * D_ + x];
    __syncthreads();
    u16* out = Vt + ((long)z * 64 + d0) * S_ + s0;
    #pragma unroll
    for (int i = 0; i < 4; i++)
        out[(long)(y + i*8) * S_ + x] = t[x][y + i*8];
}

// ------------------------------------------------- layernorm (fp32 in, bf16 out)
__global__ __launch_bounds__(256) void ln_kernel(
    const float* __restrict__ X, const float* __restrict__ alpha,
    const float* __restrict__ beta, u16* __restrict__ Y) {
    int row = blockIdx.x, tid = threadIdx.x;
    float4 xv = ((const float4*)(X + (long)row * D_))[tid];
    float v[4] = {xv.x, xv.y, xv.z, xv.w};
    float s = 0.f, ss = 0.f;
    #pragma unroll
    for (int i = 0; i < 4; i++) { s += v[i]; ss += v[i]*v[i]; }
    #pragma unroll
    for (int off = 32; off >= 1; off >>= 1) {
        s += __shfl_xor(s, off);
        ss += __shfl_xor(ss, off);
    }
    __shared__ float red[8];
    __shared__ float stats[2];
    int w = tid >> 6;
    if ((tid & 63) == 0) { red[w] = s; red[4 + w] = ss; }
    __syncthreads();
    if (tid == 0) {
        float S = red[0] + red[1] + red[2] + red[3];
        float SS = red[4] + red[5] + red[6] + red[7];
        float mean = S * (1.f / D_);
        float var = SS * (1.f / D_) - mean * mean;
        stats[0] = mean; stats[1] = rsqrtf(var + 1e-5f);
    }
    __syncthreads();
    float mean = stats[0], rstd = stats[1];
    float4 av = ((const float4*)alpha)[tid];
    float4 bv = ((const float4*)beta)[tid];
    u16x4 o;
    o[0] = f2bf((v[0] - mean) * rstd * av.x + bv.x);
    o[1] = f2bf((v[1] - mean) * rstd * av.y + bv.y);
    o[2] = f2bf((v[2] - mean) * rstd * av.z + bv.z);
    o[3] = f2bf((v[3] - mean) * rstd * av.w + bv.w);
    *(u16x4*)(Y + (long)row * D_ + tid * 4) = o;
}

// ------------------------------------------------- GEMM 256^2 8-phase (QKV fused, W1)
// R16 schedule + T2 swizzle (KEEP; R21 pinning retained, null but harmless).
#define BM2 256
#define BN2 256
#define BK2 64

__global__ __launch_bounds__(512, 2) void gemm8p(
    const u16* __restrict__ A, const u16* __restrict__ Bt,
    u16* __restrict__ C0, u16* __restrict__ C1, u16* __restrict__ C2,
    int N, int K, int mode, const float* __restrict__ bias) {
    __shared__ __align__(16) u16 lds[2 * 32768];   // 128 KB

    int tid = threadIdx.x;
    int lane = tid & 63, wave = tid >> 6;          // wave 0..7
    int l15 = lane & 15, quad = lane >> 4;
    int wm = wave & 1, wn = wave >> 1;             // M half, N quarter
    long tm0 = (long)blockIdx.y * BM2, tn0 = (long)blockIdx.x * BN2;
    int srow = lane >> 3;
    int scolw = ((lane & 7) ^ srow) * 8;           // T2 write-side inverse swizzle
    int sk = l15 & 7;
    int ca0 = ((quad) ^ sk) * 8;                   // T2 read-side
    int ca1 = ((4 + quad) ^ sk) * 8;
    int steps = K >> 6;

    auto STAGE = [&](int kt, int half, int buf) {
        long kk = (long)kt * BK2;
        #pragma unroll
        for (int c = 0; c < 2; c++) {
            int chunk = wave * 2 + c;                       // 0..15
            int rloc = (half & 1) * 128 + chunk * 8 + srow; // row in tile
            const u16* g = (half < 2)
                ? &A [(tm0 + rloc) * (long)K + kk + scolw]
                : &Bt[(tn0 + rloc) * (long)K + kk + scolw];
            u16* l = &lds[buf * 32768 + (half >= 2 ? 16384 : 0)
                          + (half & 1) * 8192 + chunk * 512];
            gload_lds16(g, l);
        }
    };

    f32x4 acc[8][4] = {};
    bf16x8 af[4][2], bl[2][2], bh[2][2];

    STAGE(0, 0, 0); STAGE(0, 1, 0); STAGE(0, 2, 0); STAGE(0, 3, 0);
    if (steps > 1) { STAGE(1, 2, 1); STAGE(1, 3, 1); }
    if (steps > 1) asm volatile("s_waitcnt vmcnt(4)" ::: "memory");
    else           asm volatile("s_waitcnt vmcnt(0)" ::: "memory");
    MBAR();

    for (int t = 0; t < steps; ++t) {
        int cur = t & 1;
        const u16* Ab = &lds[cur * 32768];
        const u16* Bb = &lds[cur * 32768 + 16384];
        bool pf1 = (t + 1 < steps), pf2 = (t + 2 < steps);

        // ph1
        #pragma unroll
        for (int mt = 0; mt < 4; mt++) {
            int row = wm*128 + mt*16 + l15;
            af[mt][0] = *(const bf16x8*)&Ab[row * BK2 + ca0];
            af[mt][1] = *(const bf16x8*)&Ab[row * BK2 + ca1];
        }
        #pragma unroll
        for (int nt = 0; nt < 2; nt++) {
            int row = wn*64 + nt*16 + l15;
            bl[nt][0] = *(const bf16x8*)&Bb[row * BK2 + ca0];
            bl[nt][1] = *(const bf16x8*)&Bb[row * BK2 + ca1];
        }
        if (pf1) STAGE(t + 1, 0, cur ^ 1);
        MBAR();
        SBAR0();
        __builtin_amdgcn_s_setprio(1);
        #pragma unroll
        for (int mt = 0; mt < 4; mt++)
            #pragma unroll
            for (int nt = 0; nt < 2; nt++) {
                acc[mt][nt] = __builtin_amdgcn_mfma_f32_16x16x32_bf16(af[mt][0], bl[nt][0], acc[mt][nt], 0,0,0);
                acc[mt][nt] = __builtin_amdgcn_mfma_f32_16x16x32_bf16(af[mt][1], bl[nt][1], acc[mt][nt], 0,0,0);
            }
        __builtin_amdgcn_s_setprio(0);
        SBAR0();
        MBAR();

        // ph2
        #pragma unroll
        for (int nt = 0; nt < 2; nt++) {
            int row = wn*64 + (2+nt)*16 + l15;
            bh[nt][0] = *(const bf16x8*)&Bb[row * BK2 + ca0];
            bh[nt][1] = *(const bf16x8*)&Bb[row * BK2 + ca1];
        }
        if (pf1) STAGE(t + 1, 1, cur ^ 1);
        MBAR();
        SBAR0();
        __builtin_amdgcn_s_setprio(1);
        #pragma unroll
        for (int mt = 0; mt < 4; mt++)
            #pragma unroll
            for (int nt = 0; nt < 2; nt++) {
                acc[mt][2+nt] = __builtin_amdgcn_mfma_f32_16x16x32_bf16(af[mt][0], bh[nt][0], acc[mt][2+nt], 0,0,0);
                acc[mt][2+nt] = __builtin_amdgcn_mfma_f32_16x16x32_bf16(af[mt][1], bh[nt][1], acc[mt][2+nt], 0,0,0);
            }
        __builtin_amdgcn_s_setprio(0);
        SBAR0();
        MBAR();

        // ph3
        #pragma unroll
        for (int mt = 0; mt < 4; mt++) {
            int row = wm*128 + 64 + mt*16 + l15;
            af[mt][0] = *(const bf16x8*)&Ab[row * BK2 + ca0];
            af[mt][1] = *(const bf16x8*)&Ab[row * BK2 + ca1];
        }
        if (pf2) STAGE(t + 2, 2, cur);
        MBAR();
        SBAR0();
        __builtin_amdgcn_s_setprio(1);
        #pragma unroll
        for (int mt = 0; mt < 4; mt++)
            #pragma unroll
            for (int nt = 0; nt < 2; nt++) {
                acc[4+mt][2+nt] = __builtin_amdgcn_mfma_f32_16x16x32_bf16(af[mt][0], bh[nt][0], acc[4+mt][2+nt], 0,0,0);
                acc[4+mt][2+nt] = __builtin_amdgcn_mfma_f32_16x16x32_bf16(af[mt][1], bh[nt][1], acc[4+mt][2+nt], 0,0,0);
            }
        __builtin_amdgcn_s_setprio(0);
        SBAR0();
        MBAR();

        // ph4
        if (pf2) STAGE(t + 2, 3, cur);
        MBAR();
        SBAR0();
        __builtin_amdgcn_s_setprio(1);
        #pragma unroll
        for (int mt = 0; mt < 4; mt++)
            #pragma unroll
            for (int nt = 0; nt < 2; nt++) {
                acc[4+mt][nt] = __builtin_amdgcn_mfma_f32_16x16x32_bf16(af[mt][0], bl[nt][0], acc[4+mt][nt], 0,0,0);
                acc[4+mt][nt] = __builtin_amdgcn_mfma_f32_16x16x32_bf16(af[mt][1], bl[nt][1], acc[4+mt][nt], 0,0,0);
            }
        __builtin_amdgcn_s_setprio(0);
        SBAR0();
        if (pf2) asm volatile("s_waitcnt vmcnt(4)" ::: "memory");
        else     asm volatile("s_waitcnt vmcnt(0)" ::: "memory");
        MBAR();
    }

    #pragma unroll
    for (int mt = 0; mt < 8; mt++) {
        #pragma unroll
        for (int nt = 0; nt < 4; nt++) {
            #pragma unroll
            for (int i = 0; i < 4; i++) {
                long r = tm0 + wm*128 + mt*16 + quad*4 + i;
                int cn = (int)tn0 + wn*64 + nt*16 + l15;
                float val = acc[mt][nt][i];
                if (mode == 0) {           // fused QKV: route to q/k/v slabs
                    int mi = cn >> 10;
                    int col = cn & 1023;
                    u16* base = (mi == 0) ? C0 : (mi == 1 ? C1 : C2);
                    base[r * 1024 + col] = f2bf(val);
                } else {                   // mode 2: bias + GELU -> bf16
                    val += bias[cn];
                    C0[r * (long)N + cn] = f2bf(gelu_fast(val));
                }
            }
        }
    }
}

// ------------------------------------------------- GEMM 256x128 8-phase (Wo, W2)
// R19 schedule (KEEP, verified).
__global__ __launch_bounds__(512, 2) void gemm8p_n128(
    const u16* __restrict__ A, const u16* __restrict__ Bt,
    float* __restrict__ C, int N, int K,
    const float* __restrict__ bias, const float* __restrict__ resid) {
    __shared__ __align__(16) u16 lds[2 * 24576];   // 96 KB

    int tid = threadIdx.x;
    int lane = tid & 63, wave = tid >> 6;          // 0..7
    int l15 = lane & 15, quad = lane >> 4;
    int wm = wave & 1, wn = wave >> 1;             // M half(128 rows), N quarter(32 cols)
    long tm0 = (long)blockIdx.y * 256, tn0 = (long)blockIdx.x * 128;
    int srow = lane >> 3;
    int scolw = ((lane & 7) ^ srow) * 8;           // T2 write-side
    int sk = l15 & 7;
    int ca0 = ((quad) ^ sk) * 8;                   // T2 read-side
    int ca1 = ((4 + quad) ^ sk) * 8;
    int steps = K >> 6;

    // half: 0=A rows 0-127 (2 ld/thr), 1=A rows 128-255 (2), 2=B rows 0-63 (1), 3=B rows 64-127 (1)
    auto STAGE = [&](int kt, int half, int buf) {
        long kk = (long)kt * 64;
        if (half < 2) {
            #pragma unroll
            for (int c = 0; c < 2; c++) {
                int chunk = wave * 2 + c;                    // 0..15
                int rloc = half * 128 + chunk * 8 + srow;
                gload_lds16(&A[(tm0 + rloc) * (long)K + kk + scolw],
                            &lds[buf * 24576 + half * 8192 + chunk * 512]);
            }
        } else {
            int rloc = (half - 2) * 64 + wave * 8 + srow;
            gload_lds16(&Bt[(tn0 + rloc) * (long)K + kk + scolw],
                        &lds[buf * 24576 + 16384 + (half - 2) * 4096 + wave * 512]);
        }
    };

    f32x4 acc[8][2] = {};
    bf16x8 af[4][2], bl[2], bh[2];

    STAGE(0, 0, 0); STAGE(0, 1, 0); STAGE(0, 2, 0); STAGE(0, 3, 0);   // 6 loads
    if (steps > 1) { STAGE(1, 2, 1); STAGE(1, 3, 1); }                 // 2 loads
    if (steps > 1) asm volatile("s_waitcnt vmcnt(2)" ::: "memory");
    else           asm volatile("s_waitcnt vmcnt(0)" ::: "memory");
    MBAR();

    for (int t = 0; t < steps; ++t) {
        int cur = t & 1;
        const u16* Ab = &lds[cur * 24576];
        const u16* Bb = &lds[cur * 24576 + 16384];
        bool pf1 = (t + 1 < steps), pf2 = (t + 2 < steps);

        // ph1: read af-mlo + bl; stage A-lo(t+1); MFMA acc[0:4][0]
        #pragma unroll
        for (int mt = 0; mt < 4; mt++) {
            int row = wm*128 + mt*16 + l15;
            af[mt][0] = *(const bf16x8*)&Ab[row * 64 + ca0];
            af[mt][1] = *(const bf16x8*)&Ab[row * 64 + ca1];
        }
        {
            int row = wn*32 + l15;
            bl[0] = *(const bf16x8*)&Bb[row * 64 + ca0];
            bl[1] = *(const bf16x8*)&Bb[row * 64 + ca1];
        }
        if (pf1) STAGE(t + 1, 0, cur ^ 1);
        MBAR();
        SBAR0();
        __builtin_amdgcn_s_setprio(1);
        #pragma unroll
        for (int mt = 0; mt < 4; mt++) {
            acc[mt][0] = __builtin_amdgcn_mfma_f32_16x16x32_bf16(af[mt][0], bl[0], acc[mt][0], 0,0,0);
            acc[mt][0] = __builtin_amdgcn_mfma_f32_16x16x32_bf16(af[mt][1], bl[1], acc[mt][0], 0,0,0);
        }
        __builtin_amdgcn_s_setprio(0);
        SBAR0();
        MBAR();

        // ph2: read bh; stage A-hi(t+1); MFMA acc[0:4][1]
        {
            int row = wn*32 + 16 + l15;
            bh[0] = *(const bf16x8*)&Bb[row * 64 + ca0];
            bh[1] = *(const bf16x8*)&Bb[row * 64 + ca1];
        }
        if (pf1) STAGE(t + 1, 1, cur ^ 1);
        MBAR();
        SBAR0();
        __builtin_amdgcn_s_setprio(1);
        #pragma unroll
        for (int mt = 0; mt < 4; mt++) {
            acc[mt][1] = __builtin_amdgcn_mfma_f32_16x16x32_bf16(af[mt][0], bh[0], acc[mt][1], 0,0,0);
            acc[mt][1] = __builtin_amdgcn_mfma_f32_16x16x32_bf16(af[mt][1], bh[1], acc[mt][1], 0,0,0);
        }
        __builtin_amdgcn_s_setprio(0);
        SBAR0();
        MBAR();

        // ph3: read af-mhi; stage B-lo(t+2); MFMA acc[4:8][1]
        #pragma unroll
        for (int mt = 0; mt < 4; mt++) {
            int row = wm*128 + 64 + mt*16 + l15;
            af[mt][0] = *(const bf16x8*)&Ab[row * 64 + ca0];
            af[mt][1] = *(const bf16x8*)&Ab[row * 64 + ca1];
        }
        if (pf2) STAGE(t + 2, 2, cur);
        MBAR();
        SBAR0();
        __builtin_amdgcn_s_setprio(1);
        #pragma unroll
        for (int mt = 0; mt < 4; mt++) {
            acc[4+mt][1] = __builtin_amdgcn_mfma_f32_16x16x32_bf16(af[mt][0], bh[0], acc[4+mt][1], 0,0,0);
            acc[4+mt][1] = __builtin_amdgcn_mfma_f32_16x16x32_bf16(af[mt][1], bh[1], acc[4+mt][1], 0,0,0);
        }
        __builtin_amdgcn_s_setprio(0);
        SBAR0();
        MBAR();

        // ph4: stage B-hi(t+2); MFMA acc[4:8][0] (bl held); tile-end counted vmcnt
        if (pf2) STAGE(t + 2, 3, cur);
        MBAR();
        SBAR0();
        __builtin_amdgcn_s_setprio(1);
        #pragma unroll
        for (int mt = 0; mt < 4; mt++) {
            acc[4+mt][0] = __builtin_amdgcn_mfma_f32_16x16x32_bf16(af[mt][0], bl[0], acc[4+mt][0], 0,0,0);
            acc[4+mt][0] = __builtin_amdgcn_mfma_f32_16x16x32_bf16(af[mt][1], bl[1], acc[4+mt][0], 0,0,0);
        }
        __builtin_amdgcn_s_setprio(0);
        SBAR0();
        if (pf2) asm volatile("s_waitcnt vmcnt(2)" ::: "memory");
        else     asm volatile("s_waitcnt vmcnt(0)" ::: "memory");
        MBAR();
    }

    #pragma unroll
    for (int mt = 0; mt < 8; mt++) {
        #pragma unroll
        for (int nt = 0; nt < 2; nt++) {
            #pragma unroll
            for (int i = 0; i < 4; i++) {
                long r = tm0 + wm*128 + mt*16 + quad*4 + i;
                int cn = (int)tn0 + wn*32 + nt*16 + l15;
                long idx = r * (long)N + cn;
                float bb = bias ? bias[cn] : 0.0f;
                C[idx] = acc[mt][nt][i] + bb + resid[idx];
            }
        }
    }
}

// ------------------------------------------------- attention
// R23: R22 swapped-operand structure with the exchange-lane bug FIXED.
// Diagnosis of R22's absmax 9.25: the nt-select `(quad<2)?x:y` ran in
// the SOURCE lane of the __shfl (shfl pulls the source's value), but
// nt_s = 2hv + (DEST quad>>1). Source lane quad_src=0 feeds dest quad 0
// (needs x) AND dest quad 2 (needs y) — one variable can't serve both.
// Fix: shuffle BOTH packs from the same addresses (8 shfl per (mt,hv))
// and select on the destination's quad<2.
// Layout (re-verified): s[mt][nt][i] = S^T[k=nt*16+quad*4+i][q=l15];
// PV B-frag needs k=hv*32+quad*8+e at elem e: src lane (quad&1)*32+l15
// (+16 for e>=4), pack nt=2hv+(quad>>1), i=e&3. ZERO LDS.
__global__ __launch_bounds__(128, 2) void attn_kernel(
    const u16* __restrict__ Q, const u16* __restrict__ Kg, const u16* __restrict__ Vt,
    const int* __restrict__ mask, u16* __restrict__ O) {
    int tid = threadIdx.x;
    int lane = tid & 63, wave = tid >> 6;            // 0..1
    int l15 = lane & 15, quad = lane >> 4;
    int bh = blockIdx.x; int b = bh >> 4, h = bh & 15;
    int j = blockIdx.y * 2 + wave;     // pair index 0..31
    long tokBase = (long)b * S_;
    const float SCL = 0.125f * 1.4426950408889634f;  // exp2 domain
    const float MMAX = 20.0f;                        // fixed softmax shift
    const int* mb = mask + b * S_;

    union U4 { u32 u[4]; bf16x8 v; };

    #pragma unroll
    for (int half = 0; half < 2; half++) {
        int t = half ? (63 - j) : j;   // q-tile index 0..63 (balanced pair)
        int q0 = t * 32;

        bf16x8 aq[2][2];
        #pragma unroll
        for (int mt = 0; mt < 2; mt++) {
            const u16* qptr = Q + (tokBase + q0 + mt*16 + l15) * D_ + h * 64;
            aq[mt][0] = *(const bf16x8*)(qptr + quad * 8);
            aq[mt][1] = *(const bf16x8*)(qptr + 32 + quad * 8);
        }

        f32x4 o[2][4] = {};
        float psum[2] = {0.f, 0.f};
        int ktiles = t / 2 + 1;

        // prefetch kb for kt=0
        bf16x8 kb[4][2];
        #pragma unroll
        for (int nt = 0; nt < 4; nt++) {
            const u16* kp = Kg + (tokBase + nt*16 + l15) * D_ + h * 64;
            kb[nt][0] = *(const bf16x8*)(kp + quad * 8);
            kb[nt][1] = *(const bf16x8*)(kp + 32 + quad * 8);
        }

        for (int kt = 0; kt < ktiles; kt++) {
            int k0 = kt * 64;
            bf16x8 vb[4][2];
            #pragma unroll
            for (int d = 0; d < 4; d++) {
                const u16* vp = Vt + ((long)bh * 64 + d*16 + l15) * S_ + k0;
                vb[d][0] = *(const bf16x8*)(vp + quad * 8);
                vb[d][1] = *(const bf16x8*)(vp + 32 + quad * 8);
            }

            // SWAPPED QK: s[mt][nt] = S^T; lane holds k=nt*16+quad*4+i, q=l15
            f32x4 s[2][4] = {};
            #pragma unroll
            for (int nt = 0; nt < 4; nt++) {
                s[0][nt] = __builtin_amdgcn_mfma_f32_16x16x32_bf16(kb[nt][0], aq[0][0], s[0][nt], 0,0,0);
                s[0][nt] = __builtin_amdgcn_mfma_f32_16x16x32_bf16(kb[nt][1], aq[0][1], s[0][nt], 0,0,0);
                s[1][nt] = __builtin_amdgcn_mfma_f32_16x16x32_bf16(kb[nt][0], aq[1][0], s[1][nt], 0,0,0);
                s[1][nt] = __builtin_amdgcn_mfma_f32_16x16x32_bf16(kb[nt][1], aq[1][1], s[1][nt], 0,0,0);
            }

            // prefetch kb(t+1) — consumed at top of next iteration
            int k1 = (kt + 1 < ktiles) ? k0 + 64 : k0;
            bf16x8 kbn[4][2];
            #pragma unroll
            for (int nt = 0; nt < 4; nt++) {
                const u16* kp = Kg + (tokBase + k1 + nt*16 + l15) * D_ + h * 64;
                kbn[nt][0] = *(const bf16x8*)(kp + quad * 8);
                kbn[nt][1] = *(const bf16x8*)(kp + 32 + quad * 8);
            }

            // attn mask bits: bit p of mv = (mask[k0+p] != 0)
            unsigned long long mv = __ballot(mb[k0 + lane] != 0);

            // in-register softmax (fixed MMAX; partials additive)
            #pragma unroll
            for (int mt = 0; mt < 2; mt++) {
                int qq = q0 + mt*16 + l15;
                #pragma unroll
                for (int nt = 0; nt < 4; nt++) {
                    #pragma unroll
                    for (int i = 0; i < 4; i++) {
                        int kloc = nt*16 + quad*4 + i;
                        float p = exp2f(fmaf(s[mt][nt][i], SCL, -MMAX));
                        bool ok = (k0 + kloc <= qq) && ((mv >> kloc) & 1ull);
                        p = ok ? p : 0.f;
                        s[mt][nt][i] = p;
                        psum[mt] += p;
                    }
                }
            }

            // pack -> exchange (both packs, dest-side select) -> PV
            bool lo = (quad < 2);
            int srcA = ((quad & 1) << 1) * 16 + l15;  // source lane for e=0..3
            #pragma unroll
            for (int mt = 0; mt < 2; mt++) {
                #pragma unroll
                for (int hv = 0; hv < 2; hv++) {
                    u32 x0 = cvtpk(s[mt][2*hv][0],   s[mt][2*hv][1]);
                    u32 x1 = cvtpk(s[mt][2*hv][2],   s[mt][2*hv][3]);
                    u32 y0 = cvtpk(s[mt][2*hv+1][0], s[mt][2*hv+1][1]);
                    u32 y1 = cvtpk(s[mt][2*hv+1][2], s[mt][2*hv+1][3]);
                    u32 gx0 = (u32)__shfl((int)x0, srcA);
                    u32 gy0 = (u32)__shfl((int)y0, srcA);
                    u32 gx1 = (u32)__shfl((int)x1, srcA);
                    u32 gy1 = (u32)__shfl((int)y1, srcA);
                    u32 gx2 = (u32)__shfl((int)x0, srcA + 16);
                    u32 gy2 = (u32)__shfl((int)y0, srcA + 16);
                    u32 gx3 = (u32)__shfl((int)x1, srcA + 16);
                    u32 gy3 = (u32)__shfl((int)y1, srcA + 16);
                    U4 pu;
                    pu.u[0] = lo ? gx0 : gy0;
                    pu.u[1] = lo ? gx1 : gy1;
                    pu.u[2] = lo ? gx2 : gy2;
                    pu.u[3] = lo ? gx3 : gy3;
                    #pragma unroll
                    for (int d = 0; d < 4; d++)
                        o[mt][d] = __builtin_amdgcn_mfma_f32_16x16x32_bf16(
                            vb[d][hv], pu.v, o[mt][d], 0,0,0);
                }
            }

            // rotate prefetched K into place
            #pragma unroll
            for (int nt = 0; nt < 4; nt++) {
                kb[nt][0] = kbn[nt][0];
                kb[nt][1] = kbn[nt][1];
            }
        }

        // denominator: reduce psum over the 4 quads sharing l15
        #pragma unroll
        for (int mt = 0; mt < 2; mt++) {
            float ps = psum[mt];
            ps += __shfl_xor(ps, 16);
            ps += __shfl_xor(ps, 32);
            float inv = 1.f / ps;
            long r = tokBase + q0 + mt*16 + l15;   // q = l15
            #pragma unroll
            for (int d = 0; d < 4; d++) {
                u16x4 ov;
                #pragma unroll
                for (int i = 0; i < 4; i++)
                    ov[i] = f2bf(o[mt][d][i] * inv);   // d_glob = d*16+quad*4+i
                *(u16x4*)(O + r * D_ + h*64 + d*16 + quad*4) = ov;
            }
        }
    }
}

// ------------------------------------------------- launch
extern "C" void kernel_launch(void* const* d_in, const int* in_sizes, int n_in,
                              void* d_out, int out_size, void* d_ws, size_t ws_size,
                              hipStream_t stream) {
    const float* x    = (const float*)d_in[0];
    const int*   am   = (const int*)d_in[1];
    const float* ln1a = (const float*)d_in[2];
    const float* ln1b = (const float*)d_in[3];
    const float* ln2a = (const float*)d_in[4];
    const float* ln2b = (const float*)d_in[5];
    const float* wq   = (const float*)d_in[6];
    const float* wk   = (const float*)d_in[7];
    const float* wv   = (const float*)d_in[8];
    const float* wo   = (const float*)d_in[9];
    const float* w1   = (const float*)d_in[10];
    const float* b1   = (const float*)d_in[11];
    const float* w2   = (const float*)d_in[12];
    const float* b2   = (const float*)d_in[13];
    float* out = (float*)d_out;

    // Workspace: 72 MB, liveness-overlapped 16MB slots.
    char* ws = (char*)d_ws;
    const size_t MB16 = (size_t)16 * 1024 * 1024;
    u16* y1      = (u16*)(ws + 0 * MB16);
    u16* q       = (u16*)(ws + 1 * MB16);
    u16* k       = (u16*)(ws + 2 * MB16);
    u16* v       = (u16*)(ws + 3 * MB16);
    u16* wqt     = (u16*)(ws + 4 * MB16 + 0 * (size_t)D_ * D_ * 2);
    u16* wkt     = (u16*)(ws + 4 * MB16 + 1 * (size_t)D_ * D_ * 2);
    u16* wvt     = (u16*)(ws + 4 * MB16 + 2 * (size_t)D_ * D_ * 2);
    u16* wot     = (u16*)(ws + 4 * MB16 + 3 * (size_t)D_ * D_ * 2);
    u16* y2      = y1;
    u16* w1t     = q;
    u16* w2t     = q + (size_t)D_ * DFF;
    u16* h_full  = k;
    u16* ctx     = v;
    u16*   vt  = (u16*)d_out;                // d_out scratch; dead after attn
    float* x1f = out;

    dim3 tb(32, 8);
    transpose_f2b4<<<dim3(D_/32, D_/32, 4), tb, 0, stream>>>(
        wq, wk, wv, wo, wqt, wkt, wvt, wot, D_, D_);

    ln_kernel<<<NT, 256, 0, stream>>>(x, ln1a, ln1b, y1);

    // fused QKV: wqt/wkt/wvt are contiguous -> one [3072][1024] B matrix
    gemm8p<<<dim3(3*D_/BN2, NT/BM2), 512, 0, stream>>>(
        y1, wqt, q, k, v, 3*D_, D_, 0, nullptr);

    transpose_v<<<dim3(S_/32, 2, B_*H_), tb, 0, stream>>>(v, vt);

    attn_kernel<<<dim3(B_*H_, 16), 128, 0, stream>>>(q, k, vt, am, ctx);

    // Wo on the 8-phase 256x128 kernel (bias=nullptr -> resid-only epilogue)
    gemm8p_n128<<<dim3(D_/128, NT/256), 512, 0, stream>>>(
        ctx, wot, x1f, D_, D_, nullptr, x);

    transpose_f2b<<<dim3(DFF/32, D_/32), tb, 0, stream>>>(w1, w1t, D_, DFF);
    transpose_f2b<<<dim3(D_/32, DFF/32), tb, 0, stream>>>(w2, w2t, DFF, D_);

    ln_kernel<<<NT, 256, 0, stream>>>(x1f, ln2a, ln2b, y2);

    gemm8p<<<dim3(DFF/BN2, NT/BM2), 512, 0, stream>>>(
        y2, w1t, h_full, h_full, h_full, DFF, D_, 2, b1);

    // W2 on the 8-phase 256x128 kernel: grid (1024/128, 8192/256) = 256 blocks
    gemm8p_n128<<<dim3(D_/128, NT/256), 512, 0, stream>>>(
        h_full, w2t, out, D_, DFF, b2, x1f);
}